// Round 6
// baseline (502.415 us; speedup 1.0000x reference)
//
#include <hip/hip_runtime.h>

typedef __attribute__((ext_vector_type(8))) short short8;
typedef __attribute__((ext_vector_type(4))) float f32x4;
typedef __attribute__((ext_vector_type(16))) float f32x16;

#define DEVFN __device__ __forceinline__

DEVFN unsigned short f2bf(float f) {
  unsigned int u = __builtin_bit_cast(unsigned int, f);
  u += 0x7FFFu + ((u >> 16) & 1u);   // RNE
  return (unsigned short)(u >> 16);
}
DEVFN float bf2f(unsigned int u) { return __builtin_bit_cast(float, u << 16); }

DEVFN unsigned int cvtpk_bf16(float lo, float hi) {
  unsigned int d;
  asm("v_cvt_pk_bf16_f32 %0, %1, %2" : "=v"(d) : "v"(lo), "v"(hi));
  return d;
}
DEVFN void plswap32(unsigned int& a, unsigned int& b) {
  asm("v_permlane32_swap_b32 %0, %1" : "+v"(a), "+v"(b));
}
DEVFN float bcast32(float v, int srclane) {
  int r = __builtin_amdgcn_ds_bpermute(srclane * 4, __builtin_bit_cast(int, v));
  return __builtin_bit_cast(float, r);
}

// ---------------- prep kernels ----------------

// cos/sin tables: [2048 pos][32 freq]
__global__ __launch_bounds__(256) void mk_tables(float* __restrict__ cost, float* __restrict__ sint) {
  int gid = blockIdx.x * 256 + threadIdx.x;   // 65536
  int pos = gid >> 5, i = gid & 31;
  float theta = powf(10000.0f, -(float)(2 * i) / 64.0f);
  float ang = (float)pos * theta;
  cost[gid] = cosf(ang);
  sint[gid] = sinf(ang);
}

__global__ __launch_bounds__(256) void bias_cat_k(const float* __restrict__ bq, const float* __restrict__ bk,
                                                  const float* __restrict__ bv, float* __restrict__ out) {
  int i = blockIdx.x * 256 + threadIdx.x;  // 3072
  float v;
  if (i < 2048) v = bq[i];
  else if (i < 2560) v = bk[i - 2048];
  else v = bv[i - 2560];
  out[i] = v;
}

__global__ __launch_bounds__(256) void convx(const float* __restrict__ x, unsigned short* __restrict__ xb) {
  int gid = blockIdx.x * 256 + threadIdx.x;   // 1048576 threads, 8 f32 each
  const float4* xv = (const float4*)x;
  float4 a = xv[(size_t)gid * 2], b = xv[(size_t)gid * 2 + 1];
  short8 u;
  u[0] = (short)f2bf(a.x); u[1] = (short)f2bf(a.y); u[2] = (short)f2bf(a.z); u[3] = (short)f2bf(a.w);
  u[4] = (short)f2bf(b.x); u[5] = (short)f2bf(b.y); u[6] = (short)f2bf(b.z); u[7] = (short)f2bf(b.w);
  *(short8*)(xb + (size_t)gid * 8) = u;
}

// W [2048][ncols] f32 -> Wt [ncols][2048] bf16 (Wt pre-offset by caller)
__global__ __launch_bounds__(256) void transw(const float* __restrict__ W, unsigned short* __restrict__ Wt, int ncols) {
  __shared__ float lds[32][33];
  int n0 = blockIdx.x * 32, k0 = blockIdx.y * 32;
  int tx = threadIdx.x & 31, ty = threadIdx.x >> 5;
  #pragma unroll
  for (int i = 0; i < 4; i++) {
    int kr = ty + i * 8;
    lds[kr][tx] = W[(size_t)(k0 + kr) * ncols + n0 + tx];
  }
  __syncthreads();
  #pragma unroll
  for (int i = 0; i < 4; i++) {
    int nr = ty + i * 8;
    Wt[(size_t)(n0 + nr) * 2048 + k0 + tx] = f2bf(lds[tx][nr]);
  }
}

// ---------------- RoPE + scatter into MFMA A-fragment order ----------------
// QKV bf16 [4096][3072] -> dst per head [tile32=t>>5][s=d>>4][lane=(d>>3&1)*32+(t&31)] x 8 elems
template<int NH>
__global__ __launch_bounds__(256) void rope_scatter(const unsigned short* __restrict__ QKV,
    const float* __restrict__ cost, const float* __restrict__ sint, const int* __restrict__ spp,
    unsigned short* __restrict__ dst, int colOff, float scale) {
  constexpr int LOG2NH = (NH == 16) ? 4 : 2;
  int gid = blockIdx.x * 256 + threadIdx.x;
  int j = gid & 63;
  int h = (gid >> 6) & (NH - 1);
  int m = gid >> (6 + LOG2NH);
  int t = m & 2047;
  int b = m >> 11;
  const unsigned short* src = QKV + (size_t)m * 3072 + colOff + h * 128 + 2 * j;
  unsigned int pair = *(const unsigned int*)src;
  float xv = bf2f(pair & 0xFFFFu), yv = bf2f(pair >> 16);
  float rx, ry;
  if (j < 32) {
    int pos = (spp[0] + t) & 2047;
    float c = cost[pos * 32 + j], s = sint[pos * 32 + j];
    rx = xv * c - yv * s;
    ry = xv * s + yv * c;
  } else { rx = xv; ry = yv; }
  rx *= scale; ry *= scale;
  int d0 = 2 * j;
  size_t off = (size_t)(b * NH + h) * 262144 + (t >> 5) * 4096 + (d0 >> 4) * 512
             + ((d0 >> 3) & 1) * 256 + (t & 31) * 8 + (d0 & 7);
  unsigned int outp = (unsigned int)f2bf(rx) | ((unsigned int)f2bf(ry) << 16);
  *(unsigned int*)(dst + off) = outp;
}

// ---------------- V transpose into PV B-fragment order ----------------
// QKV[.,2560+kh*128+d] -> VF per (b,kh): [vtile64][dt=d>>5][ks][lane=(hf)*32+(d&31)] x 8 kv-elems
__global__ __launch_bounds__(256) void vtrans(const unsigned short* __restrict__ QKV, unsigned short* __restrict__ VF) {
  __shared__ __align__(16) unsigned short lds[64 * 128];  // swizzled [t][d]
  int tid = threadIdx.x;
  int t0 = blockIdx.x * 64;
  int bk = blockIdx.y;         // b*4 + kh
  const unsigned short* src = QKV + (size_t)(bk >> 2) * 2048 * 3072 + 2560 + (bk & 3) * 128;
  #pragma unroll
  for (int c = 0; c < 4; c++) {
    int idx = c * 256 + tid;
    int tr = idx >> 4, dc = idx & 15;
    short8 v = *(const short8*)(src + (size_t)(t0 + tr) * 3072 + dc * 8);
    *(short8*)((char*)lds + tr * 256 + 16 * (dc ^ (tr >> 3))) = v;
  }
  __syncthreads();
  unsigned short* dstb = VF + (size_t)bk * 262144;
  #pragma unroll
  for (int c2 = 0; c2 < 4; c2++) {
    int idx2 = c2 * 256 + tid;
    int tc = idx2 & 7, d = idx2 >> 3;
    short8 u;
    #pragma unroll
    for (int e = 0; e < 8; e++) {
      int t = 8 * tc + e;
      u[e] = *(const short*)((char*)lds + t * 256 + 16 * ((d >> 3) ^ tc) + (d & 7) * 2);
    }
    size_t off = (size_t)(t0 >> 6) * 8192 + ((d >> 5) * 4 + ((tc >> 1) & 3)) * 512
               + (tc & 1) * 256 + (d & 31) * 8;
    *(short8*)(dstb + off) = u;
  }
}

// ---------------- GEMM: C[M][N] = A[M][K] * Bt[N][K]^T + bias, m97 structure ----------------
template<bool BF16OUT>
__global__ __launch_bounds__(256, 2) void gemm_bt(
    const unsigned short* __restrict__ A, const unsigned short* __restrict__ Bt,
    const float* __restrict__ bias, void* __restrict__ Cout, int M, int N, int K) {
  __shared__ __align__(16) unsigned short Asl[128 * 64];
  __shared__ __align__(16) unsigned short Bsl[128 * 64];
  int tid = threadIdx.x;
  int lane = tid & 63, w = tid >> 6;
  int wr = w >> 1, wc = w & 1;
  int m0 = blockIdx.y * 128, n0 = blockIdx.x * 128;

  f32x4 acc[4][4];
  #pragma unroll
  for (int i = 0; i < 4; i++)
    #pragma unroll
    for (int j = 0; j < 4; j++)
      #pragma unroll
      for (int r = 0; r < 4; r++) acc[i][j][r] = 0.f;

  int srow = w * 32 + (lane >> 3);
  int kc8 = (lane & 7) * 8;
  const unsigned short* Aptr = A + (size_t)(m0 + srow) * K + kc8;
  const unsigned short* Bptr = Bt + (size_t)(n0 + srow) * K + kc8;
  unsigned short* AslW = Asl + w * 4 * 512;
  unsigned short* BslW = Bsl + w * 4 * 512;

  for (int k0 = 0; k0 < K; k0 += 64) {
    __syncthreads();
    #pragma unroll
    for (int i = 0; i < 4; i++) {
      __builtin_amdgcn_global_load_lds(
        (const __attribute__((address_space(1))) unsigned int*)(Aptr + (size_t)i * 8 * K + k0),
        (__attribute__((address_space(3))) unsigned int*)(AslW + i * 512), 16, 0, 0);
      __builtin_amdgcn_global_load_lds(
        (const __attribute__((address_space(1))) unsigned int*)(Bptr + (size_t)i * 8 * K + k0),
        (__attribute__((address_space(3))) unsigned int*)(BslW + i * 512), 16, 0, 0);
    }
    __syncthreads();
    #pragma unroll
    for (int ks = 0; ks < 2; ks++) {
      short8 af[4], bfr[4];
      #pragma unroll
      for (int mi = 0; mi < 4; mi++)
        af[mi] = *(const short8*)(Asl + (wr * 64 + mi * 16 + (lane & 15)) * 64 + ks * 32 + (lane >> 4) * 8);
      #pragma unroll
      for (int ni = 0; ni < 4; ni++)
        bfr[ni] = *(const short8*)(Bsl + (wc * 64 + ni * 16 + (lane & 15)) * 64 + ks * 32 + (lane >> 4) * 8);
      #pragma unroll
      for (int mi = 0; mi < 4; mi++)
        #pragma unroll
        for (int ni = 0; ni < 4; ni++)
          acc[mi][ni] = __builtin_amdgcn_mfma_f32_16x16x32_bf16(af[mi], bfr[ni], acc[mi][ni], 0, 0, 0);
    }
  }
  int cl = lane & 15, rq = lane >> 4;
  #pragma unroll
  for (int mi = 0; mi < 4; mi++) {
    #pragma unroll
    for (int ni = 0; ni < 4; ni++) {
      int gn = n0 + wc * 64 + ni * 16 + cl;
      float bv = bias[gn];
      #pragma unroll
      for (int r = 0; r < 4; r++) {
        int gm = m0 + wr * 64 + mi * 16 + rq * 4 + r;
        float v = acc[mi][ni][r] + bv;
        if (BF16OUT) ((unsigned short*)Cout)[(size_t)gm * N + gn] = f2bf(v);
        else ((float*)Cout)[(size_t)gm * N + gn] = v;
      }
    }
  }
}

// ---------------- flash attention v6: barrier-free fragment loads + split-KV (2 waves/qtile) ---
// QF per (b,h): [qtile32][s][lane]x8 ; KF per (b,kh): same ; VF per (b,kh): [vtile64][dt*4+ks][lane]x8
// grid: 512 blocks x 512 thr = 4096 waves (2 per q-tile -> 4 waves/SIMD, 2 blocks/CU).
// Pair p=w>>1 owns qtile {2qg+p | 60-2qg+p}; role=w&1 splits kv tiles [0,ntA) / [ntA,nt).
// Merge at end through LDS (flash split-KV combine). bid&7 -> (b,kh): one 1MB K/V set per XCD.
__global__ __launch_bounds__(512, 4) void attn_kernel(
    const unsigned short* __restrict__ QF, const unsigned short* __restrict__ KF,
    const unsigned short* __restrict__ VF, unsigned short* __restrict__ O) {
  __shared__ float mbuf[4 * 4096];   // per pair: [64 dtr][64 lane]
  __shared__ float mlb[4 * 128];     // per pair: m[64], l[64]

  const int tid = threadIdx.x;
  const int lane = tid & 63;
  const int w = tid >> 6;
  const int p = w >> 1;
  const int role = w & 1;
  const int l31 = lane & 31;
  const int hf = lane >> 5;
  const int g = blockIdx.x & 7, j = blockIdx.x >> 3;
  const int b = g >> 2, kh = g & 3;
  const int h = kh * 4 + (j & 3);
  const int qg = j >> 2;                       // 0..15
  const int qt = (p < 2) ? (2 * qg + p) : (60 - 2 * qg + p);
  const int qw = qt * 32;
  const int nt = (qt >> 1) + 1;
  const int ntA = nt >> 1;
  const int kt0 = role ? ntA : 0;
  const int kt1 = role ? nt : ntA;

  const unsigned short* qh  = QF + (size_t)(b * 16 + h) * 262144 + qt * 4096;
  const unsigned short* khp = KF + (size_t)(b * 4 + kh) * 262144;
  const unsigned short* vhp = VF + (size_t)(b * 4 + kh) * 262144;

  short8 qf[8];
  #pragma unroll
  for (int s = 0; s < 8; s++)
    qf[s] = *(const short8*)(qh + s * 512 + lane * 8);

  float m_r = -3.0e38f, l_r = 0.f;
  f32x16 oacc[4];
  #pragma unroll
  for (int dt = 0; dt < 4; dt++)
    #pragma unroll
    for (int r = 0; r < 16; r++) oacc[dt][r] = 0.f;

  for (int kt = kt0; kt < kt1; kt++) {
    const int kv0 = kt * 64;
    // QK^T: S^T[kv][q], two 32x32 tiles; K A-fragments are lane-contiguous 1KB bursts
    f32x16 sc[2];
    {
      short8 kf0[8];
      #pragma unroll
      for (int s = 0; s < 8; s++)
        kf0[s] = *(const short8*)(khp + (size_t)(2 * kt) * 4096 + s * 512 + lane * 8);
      #pragma unroll
      for (int r = 0; r < 16; r++) sc[0][r] = 0.f;
      #pragma unroll
      for (int s = 0; s < 8; s++)
        sc[0] = __builtin_amdgcn_mfma_f32_32x32x16_bf16(kf0[s], qf[s], sc[0], 0, 0, 0);
    }
    {
      short8 kf1[8];
      #pragma unroll
      for (int s = 0; s < 8; s++)
        kf1[s] = *(const short8*)(khp + (size_t)(2 * kt + 1) * 4096 + s * 512 + lane * 8);
      #pragma unroll
      for (int r = 0; r < 16; r++) sc[1][r] = 0.f;
      #pragma unroll
      for (int s = 0; s < 8; s++)
        sc[1] = __builtin_amdgcn_mfma_f32_32x32x16_bf16(kf1[s], qf[s], sc[1], 0, 0, 0);
    }
    // issue V loads now; latency hides under softmax VALU
    short8 vf[4][4];
    #pragma unroll
    for (int dt = 0; dt < 4; dt++)
      #pragma unroll
      for (int ks = 0; ks < 4; ks++)
        vf[dt][ks] = *(const short8*)(vhp + (size_t)kt * 8192 + (dt * 4 + ks) * 512 + lane * 8);

    // causal mask (diagonal tile only): C row = kv, col = q
    if (kv0 + 63 > qw) {
      #pragma unroll
      for (int ct = 0; ct < 2; ct++)
        #pragma unroll
        for (int r = 0; r < 16; r++) {
          int kg = kv0 + ct * 32 + (r & 3) + 8 * (r >> 2) + 4 * hf;
          if (kg > qw + l31) sc[ct][r] = -3.0e38f;
        }
    }
    // row max
    float mx[16];
    #pragma unroll
    for (int r = 0; r < 16; r++) mx[r] = fmaxf(sc[0][r], sc[1][r]);
    #pragma unroll
    for (int s2 = 8; s2 >= 1; s2 >>= 1)
      #pragma unroll
      for (int i = 0; i < 8; i++) if (i < s2) mx[i] = fmaxf(mx[i], mx[i + s2]);
    float tm = fmaxf(mx[0], __shfl_xor(mx[0], 32));
    // defer-max rescale (exp2 domain, P <= 2^8)
    if (__any(tm > m_r + 8.0f)) {
      float mn = fmaxf(m_r, tm);
      float al = __builtin_amdgcn_exp2f(m_r - mn);
      m_r = mn;
      l_r *= al;
      #pragma unroll
      for (int r = 0; r < 16; r++) {
        float alr = bcast32(al, (r & 3) + 8 * (r >> 2) + 4 * hf);
        #pragma unroll
        for (int dt = 0; dt < 4; dt++) oacc[dt][r] *= alr;
      }
    }
    #pragma unroll
    for (int ct = 0; ct < 2; ct++)
      #pragma unroll
      for (int r = 0; r < 16; r++) sc[ct][r] = __builtin_amdgcn_exp2f(sc[ct][r] - m_r);
    float sm[16];
    #pragma unroll
    for (int r = 0; r < 16; r++) sm[r] = sc[0][r] + sc[1][r];
    #pragma unroll
    for (int s2 = 8; s2 >= 1; s2 >>= 1)
      #pragma unroll
      for (int i = 0; i < 8; i++) if (i < s2) sm[i] += sm[i + s2];
    l_r += sm[0];                    // partial (own 32 kv); halves combined at merge

    // repack P -> A-fragments: 16 cvt_pk + 8 permlane32_swap
    short8 pa[4];
    #pragma unroll
    for (int ks = 0; ks < 4; ks++) {
      const int ct = ks >> 1, kb = (ks & 1) * 8;
      unsigned int A0 = cvtpk_bf16(sc[ct][kb + 0], sc[ct][kb + 1]);
      unsigned int A1 = cvtpk_bf16(sc[ct][kb + 2], sc[ct][kb + 3]);
      unsigned int B0 = cvtpk_bf16(sc[ct][kb + 4], sc[ct][kb + 5]);
      unsigned int B1 = cvtpk_bf16(sc[ct][kb + 6], sc[ct][kb + 7]);
      plswap32(A0, B0);
      plswap32(A1, B1);
      union { unsigned int wds[4]; short8 s8; } u;
      u.wds[0] = A0; u.wds[1] = A1; u.wds[2] = B0; u.wds[3] = B1;
      pa[ks] = u.s8;
    }
    // PV: O[32q x 128d] += P[32x64] * V[64x128]
    #pragma unroll
    for (int dt = 0; dt < 4; dt++)
      #pragma unroll
      for (int ks = 0; ks < 4; ks++)
        oacc[dt] = __builtin_amdgcn_mfma_f32_32x32x16_bf16(pa[ks], vf[dt][ks], oacc[dt], 0, 0, 0);
  }

  // ---- split-KV merge: role1 deposits, role0 combines + writes ----
  float lw = l_r + __shfl_xor(l_r, 32);     // this wave's total l for q = qw + l31
  if (role) {
    float* bp = mbuf + p * 4096;
    #pragma unroll
    for (int dt = 0; dt < 4; dt++)
      #pragma unroll
      for (int r = 0; r < 16; r++)
        bp[(dt * 16 + r) * 64 + lane] = oacc[dt][r];
    mlb[p * 128 + lane] = m_r;
    mlb[p * 128 + 64 + lane] = lw;
  }
  __syncthreads();
  if (!role) {
    const float* bp = mbuf + p * 4096;
    float mB = mlb[p * 128 + lane];
    float lB = mlb[p * 128 + 64 + lane];
    float mm = fmaxf(m_r, mB);
    float alA = __builtin_amdgcn_exp2f(m_r - mm);
    float alB = __builtin_amdgcn_exp2f(mB - mm);
    float invl = 1.0f / (lw * alA + lB * alB);
    #pragma unroll
    for (int r = 0; r < 16; r++) {
      int rloc = (r & 3) + 8 * (r >> 2) + 4 * hf;
      float aA = bcast32(alA, rloc);
      float aB = bcast32(alB, rloc);
      float inv = bcast32(invl, rloc);
      int qgr = qw + rloc;
      unsigned short* orow = O + ((size_t)(b * 2048 + qgr)) * 2048 + h * 128;
      #pragma unroll
      for (int dt = 0; dt < 4; dt++) {
        float v = (oacc[dt][r] * aA + bp[(dt * 16 + r) * 64 + lane] * aB) * inv;
        orow[dt * 32 + l31] = f2bf(v);
      }
    }
  }
}

// ---------------- launch ----------------
extern "C" void kernel_launch(void* const* d_in, const int* in_sizes, int n_in,
                              void* d_out, int out_size, void* d_ws, size_t ws_size,
                              hipStream_t stream) {
  (void)in_sizes; (void)n_in; (void)out_size; (void)ws_size;
  const float* x  = (const float*)d_in[0];
  const float* Wq = (const float*)d_in[1];
  const float* bq = (const float*)d_in[2];
  const float* Wk = (const float*)d_in[3];
  const float* bk = (const float*)d_in[4];
  const float* Wv = (const float*)d_in[5];
  const float* bv = (const float*)d_in[6];
  const float* Wo = (const float*)d_in[7];
  const float* bo = (const float*)d_in[8];
  const int*   sp = (const int*)d_in[9];

  char* ws = (char*)d_ws;
  unsigned short* xb    = (unsigned short*)ws;                // 16,777,216 B (reused as Obuf)
  unsigned short* Wqkvt = (unsigned short*)(ws + 16777216);   // 12,582,912
  unsigned short* Wot   = (unsigned short*)(ws + 29360128);   //  8,388,608
  unsigned short* QKVb  = (unsigned short*)(ws + 37748736);   // 25,165,824 (bf16 [4096][3072])
  float* cost           = (float*)(ws + 62914560);            //    262,144
  float* sint           = (float*)(ws + 63176704);            //    262,144
  float* bcat           = (float*)(ws + 63438848);            //     12,288

  unsigned short* Obuf = xb;  // xb dead after GEMM1
  unsigned short* QFr = (unsigned short*)d_out;
  unsigned short* KFr = (unsigned short*)((char*)d_out + 16777216);
  unsigned short* VFr = (unsigned short*)((char*)d_out + 20971520);

  mk_tables<<<256, 256, 0, stream>>>(cost, sint);
  bias_cat_k<<<12, 256, 0, stream>>>(bq, bk, bv, bcat);
  convx<<<4096, 256, 0, stream>>>(x, xb);
  transw<<<dim3(64, 64), 256, 0, stream>>>(Wq, Wqkvt, 2048);
  transw<<<dim3(16, 64), 256, 0, stream>>>(Wk, Wqkvt + (size_t)2048 * 2048, 512);
  transw<<<dim3(16, 64), 256, 0, stream>>>(Wv, Wqkvt + (size_t)2560 * 2048, 512);
  transw<<<dim3(64, 64), 256, 0, stream>>>(Wo, Wot, 2048);
  gemm_bt<true><<<dim3(24, 32), 256, 0, stream>>>(xb, Wqkvt, bcat, QKVb, 4096, 3072, 2048);
  // Q scale = (1/sqrt(128)) * log2(e) so softmax can use exp2 directly
  rope_scatter<16><<<16384, 256, 0, stream>>>(QKVb, cost, sint, sp, QFr, 0, 0.12751743f);
  rope_scatter<4><<<4096, 256, 0, stream>>>(QKVb, cost, sint, sp, KFr, 2048, 1.0f);
  vtrans<<<dim3(32, 8), 256, 0, stream>>>(QKVb, VFr);
  attn_kernel<<<dim3(512), 512, 0, stream>>>(QFr, KFr, VFr, Obuf);
  gemm_bt<false><<<dim3(16, 32), 256, 0, stream>>>(Obuf, Wot, bo, (float*)d_out, 4096, 2048, 2048);
}

// Round 7
// 295.026 us; speedup vs baseline: 1.7030x; 1.7030x over previous
//
#include <hip/hip_runtime.h>

typedef __attribute__((ext_vector_type(8))) short short8;
typedef __attribute__((ext_vector_type(4))) float f32x4;
typedef __attribute__((ext_vector_type(16))) float f32x16;

#define DEVFN __device__ __forceinline__

DEVFN unsigned short f2bf(float f) {
  unsigned int u = __builtin_bit_cast(unsigned int, f);
  u += 0x7FFFu + ((u >> 16) & 1u);   // RNE
  return (unsigned short)(u >> 16);
}
DEVFN float bf2f(unsigned int u) { return __builtin_bit_cast(float, u << 16); }

DEVFN unsigned int cvtpk_bf16(float lo, float hi) {
  unsigned int d;
  asm("v_cvt_pk_bf16_f32 %0, %1, %2" : "=v"(d) : "v"(lo), "v"(hi));
  return d;
}
DEVFN void plswap32(unsigned int& a, unsigned int& b) {
  asm("v_permlane32_swap_b32 %0, %1" : "+v"(a), "+v"(b));
}
DEVFN float bcast32(float v, int srclane) {
  int r = __builtin_amdgcn_ds_bpermute(srclane * 4, __builtin_bit_cast(int, v));
  return __builtin_bit_cast(float, r);
}

// ================= fused prep: weight transposes + convx + tables + bias =================
// blocks [0,4096) Wq->Wqkvt[0:2048]  [4096,5120) Wk  [5120,6144) Wv  [6144,10240) Wo->Wot
// [10240,14336) convx  [14336,14592) tables  [14592,14604) bias concat
__global__ __launch_bounds__(256) void prep_all(
    const float* __restrict__ Wq, const float* __restrict__ Wk, const float* __restrict__ Wv,
    const float* __restrict__ Wo, const float* __restrict__ bq, const float* __restrict__ bk,
    const float* __restrict__ bv, const float* __restrict__ x,
    unsigned short* __restrict__ Wqkvt, unsigned short* __restrict__ Wot,
    unsigned short* __restrict__ xb, float* __restrict__ cost, float* __restrict__ sint,
    float* __restrict__ bcat) {
  __shared__ float lds[32][33];
  const int bid = blockIdx.x, tid = threadIdx.x;
  if (bid < 10240) {
    const float* W; unsigned short* Wt; int ncols, bx, by;
    if (bid < 4096)      { W = Wq; Wt = Wqkvt;                        ncols = 2048; bx = bid & 63; by = bid >> 6; }
    else if (bid < 5120) { int l = bid - 4096; W = Wk; Wt = Wqkvt + (size_t)2048 * 2048; ncols = 512; bx = l & 15; by = l >> 4; }
    else if (bid < 6144) { int l = bid - 5120; W = Wv; Wt = Wqkvt + (size_t)2560 * 2048; ncols = 512; bx = l & 15; by = l >> 4; }
    else                 { int l = bid - 6144; W = Wo; Wt = Wot;      ncols = 2048; bx = l & 63; by = l >> 6; }
    int n0 = bx * 32, k0 = by * 32;
    int tx = tid & 31, ty = tid >> 5;
    #pragma unroll
    for (int i = 0; i < 4; i++) {
      int kr = ty + i * 8;
      lds[kr][tx] = W[(size_t)(k0 + kr) * ncols + n0 + tx];
    }
    __syncthreads();
    #pragma unroll
    for (int i = 0; i < 4; i++) {
      int nr = ty + i * 8;
      Wt[(size_t)(n0 + nr) * 2048 + k0 + tx] = f2bf(lds[tx][nr]);
    }
  } else if (bid < 14336) {
    int gid = (bid - 10240) * 256 + tid;
    const float4* xv = (const float4*)x;
    float4 a = xv[(size_t)gid * 2], b = xv[(size_t)gid * 2 + 1];
    short8 u;
    u[0] = (short)f2bf(a.x); u[1] = (short)f2bf(a.y); u[2] = (short)f2bf(a.z); u[3] = (short)f2bf(a.w);
    u[4] = (short)f2bf(b.x); u[5] = (short)f2bf(b.y); u[6] = (short)f2bf(b.z); u[7] = (short)f2bf(b.w);
    *(short8*)(xb + (size_t)gid * 8) = u;
  } else if (bid < 14592) {
    int gid = (bid - 14336) * 256 + tid;   // 65536
    int pos = gid >> 5, i = gid & 31;
    float theta = powf(10000.0f, -(float)(2 * i) / 64.0f);
    float ang = (float)pos * theta;
    cost[gid] = cosf(ang);
    sint[gid] = sinf(ang);
  } else {
    int i = (bid - 14592) * 256 + tid;     // 3072
    float v;
    if (i < 2048) v = bq[i];
    else if (i < 2560) v = bk[i - 2048];
    else v = bv[i - 2560];
    bcat[i] = v;
  }
}

// ================= fused scatter: ropeQ + ropeK + vtrans (fragment-order outputs) =========
// blocks [0,16384) ropeQ  [16384,20480) ropeK  [20480,20736) vtrans
__global__ __launch_bounds__(256) void scatter_all(
    const unsigned short* __restrict__ QKVb, const float* __restrict__ cost,
    const float* __restrict__ sint, const int* __restrict__ spp,
    unsigned short* __restrict__ QFr, unsigned short* __restrict__ KFr,
    unsigned short* __restrict__ VFr) {
  __shared__ __align__(16) unsigned short lds[64 * 128];
  const int bid = blockIdx.x, tid = threadIdx.x;
  if (bid < 20480) {
    int NH, LOG2NH, colOff, gid;
    unsigned short* dst;
    float scale;
    if (bid < 16384) { NH = 16; LOG2NH = 4; colOff = 0;    dst = QFr; scale = 0.12751743f; gid = bid * 256 + tid; }
    else             { NH = 4;  LOG2NH = 2; colOff = 2048; dst = KFr; scale = 1.0f;        gid = (bid - 16384) * 256 + tid; }
    int j = gid & 63;
    int h = (gid >> 6) & (NH - 1);
    int m = gid >> (6 + LOG2NH);
    int t = m & 2047;
    int b = m >> 11;
    const unsigned short* src = QKVb + (size_t)m * 3072 + colOff + h * 128 + 2 * j;
    unsigned int pair = *(const unsigned int*)src;
    float xv = bf2f(pair & 0xFFFFu), yv = bf2f(pair >> 16);
    float rx, ry;
    if (j < 32) {
      int pos = (spp[0] + t) & 2047;
      float c = cost[pos * 32 + j], s = sint[pos * 32 + j];
      rx = xv * c - yv * s;
      ry = xv * s + yv * c;
    } else { rx = xv; ry = yv; }
    rx *= scale; ry *= scale;
    int d0 = 2 * j;
    size_t off = (size_t)(b * NH + h) * 262144 + (t >> 5) * 4096 + (d0 >> 4) * 512
               + ((d0 >> 3) & 1) * 256 + (t & 31) * 8 + (d0 & 7);
    unsigned int outp = (unsigned int)f2bf(rx) | ((unsigned int)f2bf(ry) << 16);
    *(unsigned int*)(dst + off) = outp;
  } else {
    int l = bid - 20480;
    int t0 = (l & 31) * 64;
    int bk = l >> 5;
    const unsigned short* src = QKVb + (size_t)(bk >> 2) * 2048 * 3072 + 2560 + (bk & 3) * 128;
    #pragma unroll
    for (int c = 0; c < 4; c++) {
      int idx = c * 256 + tid;
      int tr = idx >> 4, dc = idx & 15;
      short8 v = *(const short8*)(src + (size_t)(t0 + tr) * 3072 + dc * 8);
      *(short8*)((char*)lds + tr * 256 + 16 * (dc ^ (tr >> 3))) = v;
    }
    __syncthreads();
    unsigned short* dstb = VFr + (size_t)bk * 262144;
    #pragma unroll
    for (int c2 = 0; c2 < 4; c2++) {
      int idx2 = c2 * 256 + tid;
      int tc = idx2 & 7, d = idx2 >> 3;
      short8 u;
      #pragma unroll
      for (int e = 0; e < 8; e++) {
        int t = 8 * tc + e;
        u[e] = *(const short*)((char*)lds + t * 256 + 16 * ((d >> 3) ^ tc) + (d & 7) * 2);
      }
      size_t off = (size_t)(t0 >> 6) * 8192 + ((d >> 5) * 4 + ((tc >> 1) & 3)) * 512
                 + (tc & 1) * 256 + (d & 31) * 8;
      *(short8*)(dstb + off) = u;
    }
  }
}

// ---------------- GEMM: C[M][N] = A[M][K] * Bt[N][K]^T + bias, m97 + XCD swizzle ---------
template<bool BF16OUT>
__global__ __launch_bounds__(256, 2) void gemm_bt(
    const unsigned short* __restrict__ A, const unsigned short* __restrict__ Bt,
    const float* __restrict__ bias, void* __restrict__ Cout, int M, int N, int K, int NTX) {
  __shared__ __align__(16) unsigned short Asl[128 * 64];
  __shared__ __align__(16) unsigned short Bsl[128 * 64];
  int tid = threadIdx.x;
  int lane = tid & 63, w = tid >> 6;
  int wr = w >> 1, wc = w & 1;
  // bijective XCD swizzle (gridDim.x % 8 == 0): each XCD gets a contiguous chunk
  int f = blockIdx.x;
  int cpx = gridDim.x >> 3;
  int fs = (f & 7) * cpx + (f >> 3);
  int m0 = (fs / NTX) * 128, n0 = (fs % NTX) * 128;

  f32x4 acc[4][4];
  #pragma unroll
  for (int i = 0; i < 4; i++)
    #pragma unroll
    for (int j = 0; j < 4; j++)
      #pragma unroll
      for (int r = 0; r < 4; r++) acc[i][j][r] = 0.f;

  int srow = w * 32 + (lane >> 3);
  int kc8 = (lane & 7) * 8;
  const unsigned short* Aptr = A + (size_t)(m0 + srow) * K + kc8;
  const unsigned short* Bptr = Bt + (size_t)(n0 + srow) * K + kc8;
  unsigned short* AslW = Asl + w * 4 * 512;
  unsigned short* BslW = Bsl + w * 4 * 512;

  for (int k0 = 0; k0 < K; k0 += 64) {
    __syncthreads();
    #pragma unroll
    for (int i = 0; i < 4; i++) {
      __builtin_amdgcn_global_load_lds(
        (const __attribute__((address_space(1))) unsigned int*)(Aptr + (size_t)i * 8 * K + k0),
        (__attribute__((address_space(3))) unsigned int*)(AslW + i * 512), 16, 0, 0);
      __builtin_amdgcn_global_load_lds(
        (const __attribute__((address_space(1))) unsigned int*)(Bptr + (size_t)i * 8 * K + k0),
        (__attribute__((address_space(3))) unsigned int*)(BslW + i * 512), 16, 0, 0);
    }
    __syncthreads();
    #pragma unroll
    for (int ks = 0; ks < 2; ks++) {
      short8 af[4], bfr[4];
      #pragma unroll
      for (int mi = 0; mi < 4; mi++)
        af[mi] = *(const short8*)(Asl + (wr * 64 + mi * 16 + (lane & 15)) * 64 + ks * 32 + (lane >> 4) * 8);
      #pragma unroll
      for (int ni = 0; ni < 4; ni++)
        bfr[ni] = *(const short8*)(Bsl + (wc * 64 + ni * 16 + (lane & 15)) * 64 + ks * 32 + (lane >> 4) * 8);
      #pragma unroll
      for (int mi = 0; mi < 4; mi++)
        #pragma unroll
        for (int ni = 0; ni < 4; ni++)
          acc[mi][ni] = __builtin_amdgcn_mfma_f32_16x16x32_bf16(af[mi], bfr[ni], acc[mi][ni], 0, 0, 0);
    }
  }
  int cl = lane & 15, rq = lane >> 4;
  #pragma unroll
  for (int mi = 0; mi < 4; mi++) {
    #pragma unroll
    for (int ni = 0; ni < 4; ni++) {
      int gn = n0 + wc * 64 + ni * 16 + cl;
      float bv = bias[gn];
      #pragma unroll
      for (int r = 0; r < 4; r++) {
        int gm = m0 + wr * 64 + mi * 16 + rq * 4 + r;
        float v = acc[mi][ni][r] + bv;
        if (BF16OUT) ((unsigned short*)Cout)[(size_t)gm * N + gn] = f2bf(v);
        else ((float*)Cout)[(size_t)gm * N + gn] = v;
      }
    }
  }
}

// ---------------- flash attention v7: R5 structure + next-K dbuf + l-via-MFMA ------------
// QF per (b,h): [qtile32][s][lane]x8 ; KF per (b,kh): same ; VF per (b,kh): [vtile64][dt*4+ks][lane]x8
// grid: 256 blocks x 512 thr = 2048 waves, 1 block/CU. bid&7 -> (b,kh): one 1MB K/V set/XCD.
__global__ __launch_bounds__(512, 2) void attn_kernel(
    const unsigned short* __restrict__ QF, const unsigned short* __restrict__ KF,
    const unsigned short* __restrict__ VF, unsigned short* __restrict__ O) {
  const int tid = threadIdx.x;
  const int lane = tid & 63;
  const int w = tid >> 6;
  const int l31 = lane & 31;
  const int hf = lane >> 5;
  const int g = blockIdx.x & 7, j = blockIdx.x >> 3;
  const int b = g >> 2, kh = g & 3;
  const int h = kh * 4 + (j & 3);
  const int i4 = (j >> 2) * 4;
  const int qt = (w < 4) ? (i4 + w) : (67 - i4 - w);
  const int qw = qt * 32;
  const int nt = (qt >> 1) + 1;

  const unsigned short* qh  = QF + (size_t)(b * 16 + h) * 262144 + qt * 4096;
  const unsigned short* khp = KF + (size_t)(b * 4 + kh) * 262144;
  const unsigned short* vhp = VF + (size_t)(b * 4 + kh) * 262144;

  short8 qf[8];
  #pragma unroll
  for (int s = 0; s < 8; s++)
    qf[s] = *(const short8*)(qh + s * 512 + lane * 8);

  short8 ones;
  #pragma unroll
  for (int e = 0; e < 8; e++) ones[e] = (short)0x3F80;   // bf16 1.0

  float m_r = -3.0e38f;
  f32x16 oacc[4];
  f32x16 lacc;
  #pragma unroll
  for (int dt = 0; dt < 4; dt++)
    #pragma unroll
    for (int r = 0; r < 16; r++) oacc[dt][r] = 0.f;
  #pragma unroll
  for (int r = 0; r < 16; r++) lacc[r] = 0.f;

  short8 bufA[16], bufB[16];
  #pragma unroll
  for (int s = 0; s < 8; s++) {
    bufA[s]     = *(const short8*)(khp + s * 512 + lane * 8);
    bufA[8 + s] = *(const short8*)(khp + 4096 + s * 512 + lane * 8);
  }

  auto tileBody = [&](int kt, short8 (&kcur)[16], short8 (&knxt)[16]) {
    const int kv0 = kt * 64;
    // QK^T: S^T[kv][q], two 32x32 tiles (K prefetched into registers last tile)
    f32x16 sc[2];
    #pragma unroll
    for (int r = 0; r < 16; r++) sc[0][r] = 0.f;
    #pragma unroll
    for (int s = 0; s < 8; s++)
      sc[0] = __builtin_amdgcn_mfma_f32_32x32x16_bf16(kcur[s], qf[s], sc[0], 0, 0, 0);
    #pragma unroll
    for (int r = 0; r < 16; r++) sc[1][r] = 0.f;
    #pragma unroll
    for (int s = 0; s < 8; s++)
      sc[1] = __builtin_amdgcn_mfma_f32_32x32x16_bf16(kcur[8 + s], qf[s], sc[1], 0, 0, 0);
    // issue next tile's K loads -> land under softmax + PV
    if (kt + 1 < nt) {
      #pragma unroll
      for (int s = 0; s < 8; s++) {
        knxt[s]     = *(const short8*)(khp + (size_t)(2 * kt + 2) * 4096 + s * 512 + lane * 8);
        knxt[8 + s] = *(const short8*)(khp + (size_t)(2 * kt + 3) * 4096 + s * 512 + lane * 8);
      }
    }
    // causal mask (diagonal tile only): C row = kv, col = q
    if (kv0 + 63 > qw) {
      #pragma unroll
      for (int ct = 0; ct < 2; ct++)
        #pragma unroll
        for (int r = 0; r < 16; r++) {
          int kg = kv0 + ct * 32 + (r & 3) + 8 * (r >> 2) + 4 * hf;
          if (kg > qw + l31) sc[ct][r] = -3.0e38f;
        }
    }
    // row max over kv (in-register tree + one half-swap)
    float mx[16];
    #pragma unroll
    for (int r = 0; r < 16; r++) mx[r] = fmaxf(sc[0][r], sc[1][r]);
    #pragma unroll
    for (int s2 = 8; s2 >= 1; s2 >>= 1)
      #pragma unroll
      for (int i = 0; i < 8; i++) if (i < s2) mx[i] = fmaxf(mx[i], mx[i + s2]);
    float tm = fmaxf(mx[0], __shfl_xor(mx[0], 32));
    // defer-max rescale (exp2 domain, P <= 2^8)
    if (__any(tm > m_r + 8.0f)) {
      float mn = fmaxf(m_r, tm);
      float al = __builtin_amdgcn_exp2f(m_r - mn);
      m_r = mn;
      #pragma unroll
      for (int r = 0; r < 16; r++) {
        float alr = bcast32(al, (r & 3) + 8 * (r >> 2) + 4 * hf);
        #pragma unroll
        for (int dt = 0; dt < 4; dt++) oacc[dt][r] *= alr;
        lacc[r] *= alr;
      }
    }
    // V half A (dt=0,1): latency hides under exp + repack
    short8 vf01[8];
    #pragma unroll
    for (int q2 = 0; q2 < 8; q2++)
      vf01[q2] = *(const short8*)(vhp + (size_t)kt * 8192 + q2 * 512 + lane * 8);
    #pragma unroll
    for (int ct = 0; ct < 2; ct++)
      #pragma unroll
      for (int r = 0; r < 16; r++) sc[ct][r] = __builtin_amdgcn_exp2f(sc[ct][r] - m_r);
    // repack P -> A-fragments: 16 cvt_pk + 8 permlane32_swap
    short8 pa[4];
    #pragma unroll
    for (int ks = 0; ks < 4; ks++) {
      const int ct = ks >> 1, kb = (ks & 1) * 8;
      unsigned int A0 = cvtpk_bf16(sc[ct][kb + 0], sc[ct][kb + 1]);
      unsigned int A1 = cvtpk_bf16(sc[ct][kb + 2], sc[ct][kb + 3]);
      unsigned int B0 = cvtpk_bf16(sc[ct][kb + 4], sc[ct][kb + 5]);
      unsigned int B1 = cvtpk_bf16(sc[ct][kb + 6], sc[ct][kb + 7]);
      plswap32(A0, B0);
      plswap32(A1, B1);
      union { unsigned int wds[4]; short8 s8; } u;
      u.wds[0] = A0; u.wds[1] = A1; u.wds[2] = B0; u.wds[3] = B1;
      pa[ks] = u.s8;
    }
    // V half B (dt=2,3): latency hides under l-MFMA + PV(0,1)
    short8 vf23[8];
    #pragma unroll
    for (int q2 = 0; q2 < 8; q2++)
      vf23[q2] = *(const short8*)(vhp + (size_t)kt * 8192 + (8 + q2) * 512 + lane * 8);
    // l accumulation on the matrix pipe (replaces VALU sum tree; cols all equal)
    #pragma unroll
    for (int ks = 0; ks < 4; ks++)
      lacc = __builtin_amdgcn_mfma_f32_32x32x16_bf16(pa[ks], ones, lacc, 0, 0, 0);
    // PV: O[32q x 128d] += P[32x64] * V[64x128]
    #pragma unroll
    for (int ks = 0; ks < 4; ks++)
      oacc[0] = __builtin_amdgcn_mfma_f32_32x32x16_bf16(pa[ks], vf01[ks], oacc[0], 0, 0, 0);
    #pragma unroll
    for (int ks = 0; ks < 4; ks++)
      oacc[1] = __builtin_amdgcn_mfma_f32_32x32x16_bf16(pa[ks], vf01[4 + ks], oacc[1], 0, 0, 0);
    #pragma unroll
    for (int ks = 0; ks < 4; ks++)
      oacc[2] = __builtin_amdgcn_mfma_f32_32x32x16_bf16(pa[ks], vf23[ks], oacc[2], 0, 0, 0);
    #pragma unroll
    for (int ks = 0; ks < 4; ks++)
      oacc[3] = __builtin_amdgcn_mfma_f32_32x32x16_bf16(pa[ks], vf23[4 + ks], oacc[3], 0, 0, 0);
  };

  int kt = 0;
  while (true) {
    tileBody(kt, bufA, bufB); kt++;
    if (kt >= nt) break;
    tileBody(kt, bufB, bufA); kt++;
    if (kt >= nt) break;
  }

  // epilogue: l is already per-q-row in lacc (no cross-lane) — write O[b][q][h*128 + d]
  #pragma unroll
  for (int r = 0; r < 16; r++) {
    float inv = 1.0f / lacc[r];
    int rloc = (r & 3) + 8 * (r >> 2) + 4 * hf;
    int qgr = qw + rloc;
    unsigned short* orow = O + ((size_t)(b * 2048 + qgr)) * 2048 + h * 128;
    #pragma unroll
    for (int dt = 0; dt < 4; dt++)
      orow[dt * 32 + l31] = f2bf(oacc[dt][r] * inv);
  }
}

// ---------------- launch ----------------
extern "C" void kernel_launch(void* const* d_in, const int* in_sizes, int n_in,
                              void* d_out, int out_size, void* d_ws, size_t ws_size,
                              hipStream_t stream) {
  (void)in_sizes; (void)n_in; (void)out_size; (void)ws_size;
  const float* x  = (const float*)d_in[0];
  const float* Wq = (const float*)d_in[1];
  const float* bq = (const float*)d_in[2];
  const float* Wk = (const float*)d_in[3];
  const float* bk = (const float*)d_in[4];
  const float* Wv = (const float*)d_in[5];
  const float* bv = (const float*)d_in[6];
  const float* Wo = (const float*)d_in[7];
  const float* bo = (const float*)d_in[8];
  const int*   sp = (const int*)d_in[9];

  char* ws = (char*)d_ws;
  unsigned short* xb    = (unsigned short*)ws;                // 16,777,216 B (reused as Obuf)
  unsigned short* Wqkvt = (unsigned short*)(ws + 16777216);   // 12,582,912
  unsigned short* Wot   = (unsigned short*)(ws + 29360128);   //  8,388,608
  unsigned short* QKVb  = (unsigned short*)(ws + 37748736);   // 25,165,824 (bf16 [4096][3072])
  float* cost           = (float*)(ws + 62914560);            //    262,144
  float* sint           = (float*)(ws + 63176704);            //    262,144
  float* bcat           = (float*)(ws + 63438848);            //     12,288

  unsigned short* Obuf = xb;  // xb dead after GEMM1
  unsigned short* QFr = (unsigned short*)d_out;
  unsigned short* KFr = (unsigned short*)((char*)d_out + 16777216);
  unsigned short* VFr = (unsigned short*)((char*)d_out + 20971520);

  prep_all<<<dim3(14604), 256, 0, stream>>>(Wq, Wk, Wv, Wo, bq, bk, bv, x,
                                            Wqkvt, Wot, xb, cost, sint, bcat);
  gemm_bt<true><<<dim3(768), 256, 0, stream>>>(xb, Wqkvt, bcat, QKVb, 4096, 3072, 2048, 24);
  scatter_all<<<dim3(20736), 256, 0, stream>>>(QKVb, cost, sint, sp, QFr, KFr, VFr);
  attn_kernel<<<dim3(256), 512, 0, stream>>>(QFr, KFr, VFr, Obuf);
  gemm_bt<false><<<dim3(512), 256, 0, stream>>>(Obuf, Wot, bo, (float*)d_out, 4096, 2048, 2048, 16);
}

// Round 8
// 219.011 us; speedup vs baseline: 2.2940x; 1.3471x over previous
//
#include <hip/hip_runtime.h>

typedef __attribute__((ext_vector_type(8))) short short8;
typedef __attribute__((ext_vector_type(4))) float f32x4;
typedef __attribute__((ext_vector_type(16))) float f32x16;

#define DEVFN __device__ __forceinline__

DEVFN unsigned short f2bf(float f) {
  unsigned int u = __builtin_bit_cast(unsigned int, f);
  u += 0x7FFFu + ((u >> 16) & 1u);   // RNE
  return (unsigned short)(u >> 16);
}
DEVFN float bf2f(unsigned int u) { return __builtin_bit_cast(float, u << 16); }

DEVFN unsigned int cvtpk_bf16(float lo, float hi) {
  unsigned int d;
  asm("v_cvt_pk_bf16_f32 %0, %1, %2" : "=v"(d) : "v"(lo), "v"(hi));
  return d;
}
DEVFN void plswap32(unsigned int& a, unsigned int& b) {
  asm("v_permlane32_swap_b32 %0, %1" : "+v"(a), "+v"(b));
}
DEVFN float bcast32(float v, int srclane) {
  int r = __builtin_amdgcn_ds_bpermute(srclane * 4, __builtin_bit_cast(int, v));
  return __builtin_bit_cast(float, r);
}

// ================= fused prep: weight transposes + convx + tables + bias =================
__global__ __launch_bounds__(256) void prep_all(
    const float* __restrict__ Wq, const float* __restrict__ Wk, const float* __restrict__ Wv,
    const float* __restrict__ Wo, const float* __restrict__ bq, const float* __restrict__ bk,
    const float* __restrict__ bv, const float* __restrict__ x,
    unsigned short* __restrict__ Wqkvt, unsigned short* __restrict__ Wot,
    unsigned short* __restrict__ xb, float* __restrict__ cost, float* __restrict__ sint,
    float* __restrict__ bcat) {
  __shared__ float lds[32][33];
  const int bid = blockIdx.x, tid = threadIdx.x;
  if (bid < 10240) {
    const float* W; unsigned short* Wt; int ncols, bx, by;
    if (bid < 4096)      { W = Wq; Wt = Wqkvt;                        ncols = 2048; bx = bid & 63; by = bid >> 6; }
    else if (bid < 5120) { int l = bid - 4096; W = Wk; Wt = Wqkvt + (size_t)2048 * 2048; ncols = 512; bx = l & 15; by = l >> 4; }
    else if (bid < 6144) { int l = bid - 5120; W = Wv; Wt = Wqkvt + (size_t)2560 * 2048; ncols = 512; bx = l & 15; by = l >> 4; }
    else                 { int l = bid - 6144; W = Wo; Wt = Wot;      ncols = 2048; bx = l & 63; by = l >> 6; }
    int n0 = bx * 32, k0 = by * 32;
    int tx = tid & 31, ty = tid >> 5;
    #pragma unroll
    for (int i = 0; i < 4; i++) {
      int kr = ty + i * 8;
      lds[kr][tx] = W[(size_t)(k0 + kr) * ncols + n0 + tx];
    }
    __syncthreads();
    #pragma unroll
    for (int i = 0; i < 4; i++) {
      int nr = ty + i * 8;
      Wt[(size_t)(n0 + nr) * 2048 + k0 + tx] = f2bf(lds[tx][nr]);
    }
  } else if (bid < 14336) {
    int gid = (bid - 10240) * 256 + tid;
    const float4* xv = (const float4*)x;
    float4 a = xv[(size_t)gid * 2], b = xv[(size_t)gid * 2 + 1];
    short8 u;
    u[0] = (short)f2bf(a.x); u[1] = (short)f2bf(a.y); u[2] = (short)f2bf(a.z); u[3] = (short)f2bf(a.w);
    u[4] = (short)f2bf(b.x); u[5] = (short)f2bf(b.y); u[6] = (short)f2bf(b.z); u[7] = (short)f2bf(b.w);
    *(short8*)(xb + (size_t)gid * 8) = u;
  } else if (bid < 14592) {
    int gid = (bid - 14336) * 256 + tid;   // 65536
    int pos = gid >> 5, i = gid & 31;
    float theta = powf(10000.0f, -(float)(2 * i) / 64.0f);
    float ang = (float)pos * theta;
    cost[gid] = cosf(ang);
    sint[gid] = sinf(ang);
  } else {
    int i = (bid - 14592) * 256 + tid;     // 3072
    float v;
    if (i < 2048) v = bq[i];
    else if (i < 2560) v = bk[i - 2048];
    else v = bv[i - 2560];
    bcat[i] = v;
  }
}

// ================= fused scatter: ropeQ + ropeK + vtrans (fragment-order outputs) =========
__global__ __launch_bounds__(256) void scatter_all(
    const unsigned short* __restrict__ QKVb, const float* __restrict__ cost,
    const float* __restrict__ sint, const int* __restrict__ spp,
    unsigned short* __restrict__ QFr, unsigned short* __restrict__ KFr,
    unsigned short* __restrict__ VFr) {
  __shared__ __align__(16) unsigned short lds[64 * 128];
  const int bid = blockIdx.x, tid = threadIdx.x;
  if (bid < 20480) {
    int NH, LOG2NH, colOff, gid;
    unsigned short* dst;
    float scale;
    if (bid < 16384) { NH = 16; LOG2NH = 4; colOff = 0;    dst = QFr; scale = 0.12751743f; gid = bid * 256 + tid; }
    else             { NH = 4;  LOG2NH = 2; colOff = 2048; dst = KFr; scale = 1.0f;        gid = (bid - 16384) * 256 + tid; }
    int j = gid & 63;
    int h = (gid >> 6) & (NH - 1);
    int m = gid >> (6 + LOG2NH);
    int t = m & 2047;
    int b = m >> 11;
    const unsigned short* src = QKVb + (size_t)m * 3072 + colOff + h * 128 + 2 * j;
    unsigned int pair = *(const unsigned int*)src;
    float xv = bf2f(pair & 0xFFFFu), yv = bf2f(pair >> 16);
    float rx, ry;
    if (j < 32) {
      int pos = (spp[0] + t) & 2047;
      float c = cost[pos * 32 + j], s = sint[pos * 32 + j];
      rx = xv * c - yv * s;
      ry = xv * s + yv * c;
    } else { rx = xv; ry = yv; }
    rx *= scale; ry *= scale;
    int d0 = 2 * j;
    size_t off = (size_t)(b * NH + h) * 262144 + (t >> 5) * 4096 + (d0 >> 4) * 512
               + ((d0 >> 3) & 1) * 256 + (t & 31) * 8 + (d0 & 7);
    unsigned int outp = (unsigned int)f2bf(rx) | ((unsigned int)f2bf(ry) << 16);
    *(unsigned int*)(dst + off) = outp;
  } else {
    int l = bid - 20480;
    int t0 = (l & 31) * 64;
    int bk = l >> 5;
    const unsigned short* src = QKVb + (size_t)(bk >> 2) * 2048 * 3072 + 2560 + (bk & 3) * 128;
    #pragma unroll
    for (int c = 0; c < 4; c++) {
      int idx = c * 256 + tid;
      int tr = idx >> 4, dc = idx & 15;
      short8 v = *(const short8*)(src + (size_t)(t0 + tr) * 3072 + dc * 8);
      *(short8*)((char*)lds + tr * 256 + 16 * (dc ^ (tr >> 3))) = v;
    }
    __syncthreads();
    unsigned short* dstb = VFr + (size_t)bk * 262144;
    #pragma unroll
    for (int c2 = 0; c2 < 4; c2++) {
      int idx2 = c2 * 256 + tid;
      int tc = idx2 & 7, d = idx2 >> 3;
      short8 u;
      #pragma unroll
      for (int e = 0; e < 8; e++) {
        int t = 8 * tc + e;
        u[e] = *(const short*)((char*)lds + t * 256 + 16 * ((d >> 3) ^ tc) + (d & 7) * 2);
      }
      size_t off = (size_t)(t0 >> 6) * 8192 + ((d >> 5) * 4 + ((tc >> 1) & 3)) * 512
                 + (tc & 1) * 256 + (d & 31) * 8;
      *(short8*)(dstb + off) = u;
    }
  }
}

// ---------------- GEMM: C[M][N] = A[M][K] * Bt[N][K]^T + bias, m97 + XCD swizzle ---------
template<bool BF16OUT>
__global__ __launch_bounds__(256, 2) void gemm_bt(
    const unsigned short* __restrict__ A, const unsigned short* __restrict__ Bt,
    const float* __restrict__ bias, void* __restrict__ Cout, int M, int N, int K, int NTX) {
  __shared__ __align__(16) unsigned short Asl[128 * 64];
  __shared__ __align__(16) unsigned short Bsl[128 * 64];
  int tid = threadIdx.x;
  int lane = tid & 63, w = tid >> 6;
  int wr = w >> 1, wc = w & 1;
  int f = blockIdx.x;
  int cpx = gridDim.x >> 3;
  int fs = (f & 7) * cpx + (f >> 3);
  int m0 = (fs / NTX) * 128, n0 = (fs % NTX) * 128;

  f32x4 acc[4][4];
  #pragma unroll
  for (int i = 0; i < 4; i++)
    #pragma unroll
    for (int j = 0; j < 4; j++)
      #pragma unroll
      for (int r = 0; r < 4; r++) acc[i][j][r] = 0.f;

  int srow = w * 32 + (lane >> 3);
  int kc8 = (lane & 7) * 8;
  const unsigned short* Aptr = A + (size_t)(m0 + srow) * K + kc8;
  const unsigned short* Bptr = Bt + (size_t)(n0 + srow) * K + kc8;
  unsigned short* AslW = Asl + w * 4 * 512;
  unsigned short* BslW = Bsl + w * 4 * 512;

  for (int k0 = 0; k0 < K; k0 += 64) {
    __syncthreads();
    #pragma unroll
    for (int i = 0; i < 4; i++) {
      __builtin_amdgcn_global_load_lds(
        (const __attribute__((address_space(1))) unsigned int*)(Aptr + (size_t)i * 8 * K + k0),
        (__attribute__((address_space(3))) unsigned int*)(AslW + i * 512), 16, 0, 0);
      __builtin_amdgcn_global_load_lds(
        (const __attribute__((address_space(1))) unsigned int*)(Bptr + (size_t)i * 8 * K + k0),
        (__attribute__((address_space(3))) unsigned int*)(BslW + i * 512), 16, 0, 0);
    }
    __syncthreads();
    #pragma unroll
    for (int ks = 0; ks < 2; ks++) {
      short8 af[4], bfr[4];
      #pragma unroll
      for (int mi = 0; mi < 4; mi++)
        af[mi] = *(const short8*)(Asl + (wr * 64 + mi * 16 + (lane & 15)) * 64 + ks * 32 + (lane >> 4) * 8);
      #pragma unroll
      for (int ni = 0; ni < 4; ni++)
        bfr[ni] = *(const short8*)(Bsl + (wc * 64 + ni * 16 + (lane & 15)) * 64 + ks * 32 + (lane >> 4) * 8);
      #pragma unroll
      for (int mi = 0; mi < 4; mi++)
        #pragma unroll
        for (int ni = 0; ni < 4; ni++)
          acc[mi][ni] = __builtin_amdgcn_mfma_f32_16x16x32_bf16(af[mi], bfr[ni], acc[mi][ni], 0, 0, 0);
    }
  }
  int cl = lane & 15, rq = lane >> 4;
  #pragma unroll
  for (int mi = 0; mi < 4; mi++) {
    #pragma unroll
    for (int ni = 0; ni < 4; ni++) {
      int gn = n0 + wc * 64 + ni * 16 + cl;
      float bv = bias[gn];
      #pragma unroll
      for (int r = 0; r < 4; r++) {
        int gm = m0 + wr * 64 + mi * 16 + rq * 4 + r;
        float v = acc[mi][ni][r] + bv;
        if (BF16OUT) ((unsigned short*)Cout)[(size_t)gm * N + gn] = f2bf(v);
        else ((float*)Cout)[(size_t)gm * N + gn] = v;
      }
    }
  }
}

// ---------------- flash attention v8: R5 structure + l-via-MFMA, 256-VGPR bounds ---------
// QF per (b,h): [qtile32][s][lane]x8 ; KF per (b,kh): same ; VF per (b,kh): [vtile64][dt*4+ks][lane]x8
// grid: 256 blocks x 512 thr = 2048 waves, 1 block/CU (grid-limited to 2 waves/SIMD).
// NOTE: 2nd launch_bounds arg acts as blocks/CU on this toolchain (R5/R6/R7 VGPR evidence:
// (512,4)->64, (512,2)->128); use 1 to unlock 256 VGPRs — occupancy is grid-limited anyway.
__global__ __launch_bounds__(512, 1) void attn_kernel(
    const unsigned short* __restrict__ QF, const unsigned short* __restrict__ KF,
    const unsigned short* __restrict__ VF, unsigned short* __restrict__ O) {
  const int tid = threadIdx.x;
  const int lane = tid & 63;
  const int w = tid >> 6;
  const int l31 = lane & 31;
  const int hf = lane >> 5;
  const int g = blockIdx.x & 7, j = blockIdx.x >> 3;
  const int b = g >> 2, kh = g & 3;
  const int h = kh * 4 + (j & 3);
  const int i4 = (j >> 2) * 4;
  const int qt = (w < 4) ? (i4 + w) : (67 - i4 - w);
  const int qw = qt * 32;
  const int nt = (qt >> 1) + 1;

  const unsigned short* qh  = QF + (size_t)(b * 16 + h) * 262144 + qt * 4096;
  const unsigned short* khp = KF + (size_t)(b * 4 + kh) * 262144;
  const unsigned short* vhp = VF + (size_t)(b * 4 + kh) * 262144;

  short8 qf[8];
  #pragma unroll
  for (int s = 0; s < 8; s++)
    qf[s] = *(const short8*)(qh + s * 512 + lane * 8);

  short8 ones;
  #pragma unroll
  for (int e = 0; e < 8; e++) ones[e] = (short)0x3F80;   // bf16 1.0

  float m_r = -3.0e38f;
  f32x16 oacc[4];
  f32x16 lacc;
  #pragma unroll
  for (int dt = 0; dt < 4; dt++)
    #pragma unroll
    for (int r = 0; r < 16; r++) oacc[dt][r] = 0.f;
  #pragma unroll
  for (int r = 0; r < 16; r++) lacc[r] = 0.f;

  for (int kt = 0; kt < nt; kt++) {
    const int kv0 = kt * 64;
    // QK^T: S^T[kv][q], two 32x32 tiles; K A-fragments are lane-contiguous 1KB bursts
    f32x16 sc[2];
    {
      short8 kf0[8];
      #pragma unroll
      for (int s = 0; s < 8; s++)
        kf0[s] = *(const short8*)(khp + (size_t)(2 * kt) * 4096 + s * 512 + lane * 8);
      #pragma unroll
      for (int r = 0; r < 16; r++) sc[0][r] = 0.f;
      #pragma unroll
      for (int s = 0; s < 8; s++)
        sc[0] = __builtin_amdgcn_mfma_f32_32x32x16_bf16(kf0[s], qf[s], sc[0], 0, 0, 0);
    }
    {
      short8 kf1[8];
      #pragma unroll
      for (int s = 0; s < 8; s++)
        kf1[s] = *(const short8*)(khp + (size_t)(2 * kt + 1) * 4096 + s * 512 + lane * 8);
      #pragma unroll
      for (int r = 0; r < 16; r++) sc[1][r] = 0.f;
      #pragma unroll
      for (int s = 0; s < 8; s++)
        sc[1] = __builtin_amdgcn_mfma_f32_32x32x16_bf16(kf1[s], qf[s], sc[1], 0, 0, 0);
    }
    // issue V loads now; latency hides under softmax VALU
    short8 vf[4][4];
    #pragma unroll
    for (int dt = 0; dt < 4; dt++)
      #pragma unroll
      for (int ks = 0; ks < 4; ks++)
        vf[dt][ks] = *(const short8*)(vhp + (size_t)kt * 8192 + (dt * 4 + ks) * 512 + lane * 8);

    // causal mask (diagonal tile only): C row = kv, col = q
    if (kv0 + 63 > qw) {
      #pragma unroll
      for (int ct = 0; ct < 2; ct++)
        #pragma unroll
        for (int r = 0; r < 16; r++) {
          int kg = kv0 + ct * 32 + (r & 3) + 8 * (r >> 2) + 4 * hf;
          if (kg > qw + l31) sc[ct][r] = -3.0e38f;
        }
    }
    // row max
    float mx[16];
    #pragma unroll
    for (int r = 0; r < 16; r++) mx[r] = fmaxf(sc[0][r], sc[1][r]);
    #pragma unroll
    for (int s2 = 8; s2 >= 1; s2 >>= 1)
      #pragma unroll
      for (int i = 0; i < 8; i++) if (i < s2) mx[i] = fmaxf(mx[i], mx[i + s2]);
    float tm = fmaxf(mx[0], __shfl_xor(mx[0], 32));
    // defer-max rescale (exp2 domain, P <= 2^8)
    if (__any(tm > m_r + 8.0f)) {
      float mn = fmaxf(m_r, tm);
      float al = __builtin_amdgcn_exp2f(m_r - mn);
      m_r = mn;
      #pragma unroll
      for (int r = 0; r < 16; r++) {
        float alr = bcast32(al, (r & 3) + 8 * (r >> 2) + 4 * hf);
        #pragma unroll
        for (int dt = 0; dt < 4; dt++) oacc[dt][r] *= alr;
        lacc[r] *= alr;
      }
    }
    #pragma unroll
    for (int ct = 0; ct < 2; ct++)
      #pragma unroll
      for (int r = 0; r < 16; r++) sc[ct][r] = __builtin_amdgcn_exp2f(sc[ct][r] - m_r);

    // repack P -> A-fragments: 16 cvt_pk + 8 permlane32_swap
    short8 pa[4];
    #pragma unroll
    for (int ks = 0; ks < 4; ks++) {
      const int ct = ks >> 1, kb = (ks & 1) * 8;
      unsigned int A0 = cvtpk_bf16(sc[ct][kb + 0], sc[ct][kb + 1]);
      unsigned int A1 = cvtpk_bf16(sc[ct][kb + 2], sc[ct][kb + 3]);
      unsigned int B0 = cvtpk_bf16(sc[ct][kb + 4], sc[ct][kb + 5]);
      unsigned int B1 = cvtpk_bf16(sc[ct][kb + 6], sc[ct][kb + 7]);
      plswap32(A0, B0);
      plswap32(A1, B1);
      union { unsigned int wds[4]; short8 s8; } u;
      u.wds[0] = A0; u.wds[1] = A1; u.wds[2] = B0; u.wds[3] = B1;
      pa[ks] = u.s8;
    }
    // l accumulation on the matrix pipe (replaces the VALU sum tree; all C cols equal)
    #pragma unroll
    for (int ks = 0; ks < 4; ks++)
      lacc = __builtin_amdgcn_mfma_f32_32x32x16_bf16(pa[ks], ones, lacc, 0, 0, 0);
    // PV: O[32q x 128d] += P[32x64] * V[64x128]
    #pragma unroll
    for (int dt = 0; dt < 4; dt++)
      #pragma unroll
      for (int ks = 0; ks < 4; ks++)
        oacc[dt] = __builtin_amdgcn_mfma_f32_32x32x16_bf16(pa[ks], vf[dt][ks], oacc[dt], 0, 0, 0);
  }
  // epilogue: lacc[r] = row sum over all kv (no cross-lane needed)
  #pragma unroll
  for (int r = 0; r < 16; r++) {
    float inv = 1.0f / lacc[r];
    int rloc = (r & 3) + 8 * (r >> 2) + 4 * hf;
    int qgr = qw + rloc;
    unsigned short* orow = O + ((size_t)(b * 2048 + qgr)) * 2048 + h * 128;
    #pragma unroll
    for (int dt = 0; dt < 4; dt++)
      orow[dt * 32 + l31] = f2bf(oacc[dt][r] * inv);
  }
}

// ---------------- launch ----------------
extern "C" void kernel_launch(void* const* d_in, const int* in_sizes, int n_in,
                              void* d_out, int out_size, void* d_ws, size_t ws_size,
                              hipStream_t stream) {
  (void)in_sizes; (void)n_in; (void)out_size; (void)ws_size;
  const float* x  = (const float*)d_in[0];
  const float* Wq = (const float*)d_in[1];
  const float* bq = (const float*)d_in[2];
  const float* Wk = (const float*)d_in[3];
  const float* bk = (const float*)d_in[4];
  const float* Wv = (const float*)d_in[5];
  const float* bv = (const float*)d_in[6];
  const float* Wo = (const float*)d_in[7];
  const float* bo = (const float*)d_in[8];
  const int*   sp = (const int*)d_in[9];

  char* ws = (char*)d_ws;
  unsigned short* xb    = (unsigned short*)ws;                // 16,777,216 B (reused as Obuf)
  unsigned short* Wqkvt = (unsigned short*)(ws + 16777216);   // 12,582,912
  unsigned short* Wot   = (unsigned short*)(ws + 29360128);   //  8,388,608
  unsigned short* QKVb  = (unsigned short*)(ws + 37748736);   // 25,165,824 (bf16 [4096][3072])
  float* cost           = (float*)(ws + 62914560);            //    262,144
  float* sint           = (float*)(ws + 63176704);            //    262,144
  float* bcat           = (float*)(ws + 63438848);            //     12,288

  unsigned short* Obuf = xb;  // xb dead after GEMM1
  unsigned short* QFr = (unsigned short*)d_out;
  unsigned short* KFr = (unsigned short*)((char*)d_out + 16777216);
  unsigned short* VFr = (unsigned short*)((char*)d_out + 20971520);

  prep_all<<<dim3(14604), 256, 0, stream>>>(Wq, Wk, Wv, Wo, bq, bk, bv, x,
                                            Wqkvt, Wot, xb, cost, sint, bcat);
  gemm_bt<true><<<dim3(768), 256, 0, stream>>>(xb, Wqkvt, bcat, QKVb, 4096, 3072, 2048, 24);
  scatter_all<<<dim3(20736), 256, 0, stream>>>(QKVb, cost, sint, sp, QFr, KFr, VFr);
  attn_kernel<<<dim3(256), 512, 0, stream>>>(QFr, KFr, VFr, Obuf);
  gemm_bt<false><<<dim3(512), 256, 0, stream>>>(Obuf, Wot, bo, (float*)d_out, 4096, 2048, 2048, 16);
}

// Round 9
// 218.456 us; speedup vs baseline: 2.2998x; 1.0025x over previous
//
#include <hip/hip_runtime.h>

typedef __attribute__((ext_vector_type(8))) short short8;
typedef __attribute__((ext_vector_type(4))) float f32x4;
typedef __attribute__((ext_vector_type(16))) float f32x16;

#define DEVFN __device__ __forceinline__

DEVFN unsigned short f2bf(float f) {
  unsigned int u = __builtin_bit_cast(unsigned int, f);
  u += 0x7FFFu + ((u >> 16) & 1u);   // RNE
  return (unsigned short)(u >> 16);
}
DEVFN float bf2f(unsigned int u) { return __builtin_bit_cast(float, u << 16); }

DEVFN unsigned int cvtpk_bf16(float lo, float hi) {
  unsigned int d;
  asm("v_cvt_pk_bf16_f32 %0, %1, %2" : "=v"(d) : "v"(lo), "v"(hi));
  return d;
}
DEVFN void plswap32(unsigned int& a, unsigned int& b) {
  asm("v_permlane32_swap_b32 %0, %1" : "+v"(a), "+v"(b));
}
DEVFN float bcast32(float v, int srclane) {
  int r = __builtin_amdgcn_ds_bpermute(srclane * 4, __builtin_bit_cast(int, v));
  return __builtin_bit_cast(float, r);
}

// ================= fused prep: weight transposes + convx + tables + bias =================
__global__ __launch_bounds__(256) void prep_all(
    const float* __restrict__ Wq, const float* __restrict__ Wk, const float* __restrict__ Wv,
    const float* __restrict__ Wo, const float* __restrict__ bq, const float* __restrict__ bk,
    const float* __restrict__ bv, const float* __restrict__ x,
    unsigned short* __restrict__ Wqkvt, unsigned short* __restrict__ Wot,
    unsigned short* __restrict__ xb, float* __restrict__ cost, float* __restrict__ sint,
    float* __restrict__ bcat) {
  __shared__ float lds[32][33];
  const int bid = blockIdx.x, tid = threadIdx.x;
  if (bid < 10240) {
    const float* W; unsigned short* Wt; int ncols, bx, by;
    if (bid < 4096)      { W = Wq; Wt = Wqkvt;                        ncols = 2048; bx = bid & 63; by = bid >> 6; }
    else if (bid < 5120) { int l = bid - 4096; W = Wk; Wt = Wqkvt + (size_t)2048 * 2048; ncols = 512; bx = l & 15; by = l >> 4; }
    else if (bid < 6144) { int l = bid - 5120; W = Wv; Wt = Wqkvt + (size_t)2560 * 2048; ncols = 512; bx = l & 15; by = l >> 4; }
    else                 { int l = bid - 6144; W = Wo; Wt = Wot;      ncols = 2048; bx = l & 63; by = l >> 6; }
    int n0 = bx * 32, k0 = by * 32;
    int tx = tid & 31, ty = tid >> 5;
    #pragma unroll
    for (int i = 0; i < 4; i++) {
      int kr = ty + i * 8;
      lds[kr][tx] = W[(size_t)(k0 + kr) * ncols + n0 + tx];
    }
    __syncthreads();
    #pragma unroll
    for (int i = 0; i < 4; i++) {
      int nr = ty + i * 8;
      Wt[(size_t)(n0 + nr) * 2048 + k0 + tx] = f2bf(lds[tx][nr]);
    }
  } else if (bid < 14336) {
    int gid = (bid - 10240) * 256 + tid;
    const float4* xv = (const float4*)x;
    float4 a = xv[(size_t)gid * 2], b = xv[(size_t)gid * 2 + 1];
    short8 u;
    u[0] = (short)f2bf(a.x); u[1] = (short)f2bf(a.y); u[2] = (short)f2bf(a.z); u[3] = (short)f2bf(a.w);
    u[4] = (short)f2bf(b.x); u[5] = (short)f2bf(b.y); u[6] = (short)f2bf(b.z); u[7] = (short)f2bf(b.w);
    *(short8*)(xb + (size_t)gid * 8) = u;
  } else if (bid < 14592) {
    int gid = (bid - 14336) * 256 + tid;   // 65536
    int pos = gid >> 5, i = gid & 31;
    float theta = powf(10000.0f, -(float)(2 * i) / 64.0f);
    float ang = (float)pos * theta;
    cost[gid] = cosf(ang);
    sint[gid] = sinf(ang);
  } else {
    int i = (bid - 14592) * 256 + tid;     // 3072
    float v;
    if (i < 2048) v = bq[i];
    else if (i < 2560) v = bk[i - 2048];
    else v = bv[i - 2560];
    bcat[i] = v;
  }
}

// ================= fused scatter: ropeQ + ropeK + vtrans (fragment-order outputs) =========
__global__ __launch_bounds__(256) void scatter_all(
    const unsigned short* __restrict__ QKVb, const float* __restrict__ cost,
    const float* __restrict__ sint, const int* __restrict__ spp,
    unsigned short* __restrict__ QFr, unsigned short* __restrict__ KFr,
    unsigned short* __restrict__ VFr) {
  __shared__ __align__(16) unsigned short lds[64 * 128];
  const int bid = blockIdx.x, tid = threadIdx.x;
  if (bid < 20480) {
    int NH, LOG2NH, colOff, gid;
    unsigned short* dst;
    float scale;
    if (bid < 16384) { NH = 16; LOG2NH = 4; colOff = 0;    dst = QFr; scale = 0.12751743f; gid = bid * 256 + tid; }
    else             { NH = 4;  LOG2NH = 2; colOff = 2048; dst = KFr; scale = 1.0f;        gid = (bid - 16384) * 256 + tid; }
    int j = gid & 63;
    int h = (gid >> 6) & (NH - 1);
    int m = gid >> (6 + LOG2NH);
    int t = m & 2047;
    int b = m >> 11;
    const unsigned short* src = QKVb + (size_t)m * 3072 + colOff + h * 128 + 2 * j;
    unsigned int pair = *(const unsigned int*)src;
    float xv = bf2f(pair & 0xFFFFu), yv = bf2f(pair >> 16);
    float rx, ry;
    if (j < 32) {
      int pos = (spp[0] + t) & 2047;
      float c = cost[pos * 32 + j], s = sint[pos * 32 + j];
      rx = xv * c - yv * s;
      ry = xv * s + yv * c;
    } else { rx = xv; ry = yv; }
    rx *= scale; ry *= scale;
    int d0 = 2 * j;
    size_t off = (size_t)(b * NH + h) * 262144 + (t >> 5) * 4096 + (d0 >> 4) * 512
               + ((d0 >> 3) & 1) * 256 + (t & 31) * 8 + (d0 & 7);
    unsigned int outp = (unsigned int)f2bf(rx) | ((unsigned int)f2bf(ry) << 16);
    *(unsigned int*)(dst + off) = outp;
  } else {
    int l = bid - 20480;
    int t0 = (l & 31) * 64;
    int bk = l >> 5;
    const unsigned short* src = QKVb + (size_t)(bk >> 2) * 2048 * 3072 + 2560 + (bk & 3) * 128;
    #pragma unroll
    for (int c = 0; c < 4; c++) {
      int idx = c * 256 + tid;
      int tr = idx >> 4, dc = idx & 15;
      short8 v = *(const short8*)(src + (size_t)(t0 + tr) * 3072 + dc * 8);
      *(short8*)((char*)lds + tr * 256 + 16 * (dc ^ (tr >> 3))) = v;
    }
    __syncthreads();
    unsigned short* dstb = VFr + (size_t)bk * 262144;
    #pragma unroll
    for (int c2 = 0; c2 < 4; c2++) {
      int idx2 = c2 * 256 + tid;
      int tc = idx2 & 7, d = idx2 >> 3;
      short8 u;
      #pragma unroll
      for (int e = 0; e < 8; e++) {
        int t = 8 * tc + e;
        u[e] = *(const short*)((char*)lds + t * 256 + 16 * ((d >> 3) ^ tc) + (d & 7) * 2);
      }
      size_t off = (size_t)(t0 >> 6) * 8192 + ((d >> 5) * 4 + ((tc >> 1) & 3)) * 512
                 + (tc & 1) * 256 + (d & 31) * 8;
      *(short8*)(dstb + off) = u;
    }
  }
}

// ---------------- GEMM: C[M][N] = A[M][K] * Bt[N][K]^T + bias, m97 + XCD swizzle ---------
template<bool BF16OUT>
__global__ __launch_bounds__(256, 2) void gemm_bt(
    const unsigned short* __restrict__ A, const unsigned short* __restrict__ Bt,
    const float* __restrict__ bias, void* __restrict__ Cout, int M, int N, int K, int NTX) {
  __shared__ __align__(16) unsigned short Asl[128 * 64];
  __shared__ __align__(16) unsigned short Bsl[128 * 64];
  int tid = threadIdx.x;
  int lane = tid & 63, w = tid >> 6;
  int wr = w >> 1, wc = w & 1;
  int f = blockIdx.x;
  int cpx = gridDim.x >> 3;
  int fs = (f & 7) * cpx + (f >> 3);
  int m0 = (fs / NTX) * 128, n0 = (fs % NTX) * 128;

  f32x4 acc[4][4];
  #pragma unroll
  for (int i = 0; i < 4; i++)
    #pragma unroll
    for (int j = 0; j < 4; j++)
      #pragma unroll
      for (int r = 0; r < 4; r++) acc[i][j][r] = 0.f;

  int srow = w * 32 + (lane >> 3);
  int kc8 = (lane & 7) * 8;
  const unsigned short* Aptr = A + (size_t)(m0 + srow) * K + kc8;
  const unsigned short* Bptr = Bt + (size_t)(n0 + srow) * K + kc8;
  unsigned short* AslW = Asl + w * 4 * 512;
  unsigned short* BslW = Bsl + w * 4 * 512;

  for (int k0 = 0; k0 < K; k0 += 64) {
    __syncthreads();
    #pragma unroll
    for (int i = 0; i < 4; i++) {
      __builtin_amdgcn_global_load_lds(
        (const __attribute__((address_space(1))) unsigned int*)(Aptr + (size_t)i * 8 * K + k0),
        (__attribute__((address_space(3))) unsigned int*)(AslW + i * 512), 16, 0, 0);
      __builtin_amdgcn_global_load_lds(
        (const __attribute__((address_space(1))) unsigned int*)(Bptr + (size_t)i * 8 * K + k0),
        (__attribute__((address_space(3))) unsigned int*)(BslW + i * 512), 16, 0, 0);
    }
    __syncthreads();
    #pragma unroll
    for (int ks = 0; ks < 2; ks++) {
      short8 af[4], bfr[4];
      #pragma unroll
      for (int mi = 0; mi < 4; mi++)
        af[mi] = *(const short8*)(Asl + (wr * 64 + mi * 16 + (lane & 15)) * 64 + ks * 32 + (lane >> 4) * 8);
      #pragma unroll
      for (int ni = 0; ni < 4; ni++)
        bfr[ni] = *(const short8*)(Bsl + (wc * 64 + ni * 16 + (lane & 15)) * 64 + ks * 32 + (lane >> 4) * 8);
      #pragma unroll
      for (int mi = 0; mi < 4; mi++)
        #pragma unroll
        for (int ni = 0; ni < 4; ni++)
          acc[mi][ni] = __builtin_amdgcn_mfma_f32_16x16x32_bf16(af[mi], bfr[ni], acc[mi][ni], 0, 0, 0);
    }
  }
  int cl = lane & 15, rq = lane >> 4;
  #pragma unroll
  for (int mi = 0; mi < 4; mi++) {
    #pragma unroll
    for (int ni = 0; ni < 4; ni++) {
      int gn = n0 + wc * 64 + ni * 16 + cl;
      float bv = bias[gn];
      #pragma unroll
      for (int r = 0; r < 4; r++) {
        int gm = m0 + wr * 64 + mi * 16 + rq * 4 + r;
        float v = acc[mi][ni][r] + bv;
        if (BF16OUT) ((unsigned short*)Cout)[(size_t)gm * N + gn] = f2bf(v);
        else ((float*)Cout)[(size_t)gm * N + gn] = v;
      }
    }
  }
}

// ---------------- flash attention v9: LDS-shared K/V (global_load_lds dbuf), 4 waves -----
// QF per (b,h): [qtile32][s][lane]x8 ; KF/VF per (b,kh): [kv64tile][slice16][lane]x8
// grid: 512 blocks x 256 thr, 2 blocks/CU. Block: 4 consecutive q-tiles (qg*4+w) of one
// (b,h) -> waves differ by <=2 KV tiles; K/V staged ONCE per block per tile (L2 traffic /4).
// qg(bid) pairs g with 15-g across the two residency rounds for cross-CU balance.
// bid&7 -> (b,kh): one 1MB K/V set per XCD.
__global__ __launch_bounds__(256, 2) void attn_kernel(
    const unsigned short* __restrict__ QF, const unsigned short* __restrict__ KF,
    const unsigned short* __restrict__ VF, unsigned short* __restrict__ O) {
  __shared__ __align__(16) unsigned short Kl[2][8192];   // 2 x 16KB: [slice16][lane8]
  __shared__ __align__(16) unsigned short Vl[2][8192];   // 2 x 16KB

  const int tid = threadIdx.x;
  const int lane = tid & 63;
  const int w = tid >> 6;
  const int l31 = lane & 31;
  const int hf = lane >> 5;
  const int bid = blockIdx.x;
  const int g8 = bid & 7;
  const int b = g8 >> 2, kh = g8 & 3;
  const int h = kh * 4 + ((bid >> 3) & 3);
  const int qg = (bid < 256) ? (bid >> 5) : (15 - ((bid - 256) >> 5));
  const int qt = qg * 4 + w;
  const int qw = qt * 32;
  const int ntw = (qt >> 1) + 1;     // tiles this wave computes
  const int nbt = 2 * qg + 2;        // tiles this block stages (= ntw of wave 3)

  const unsigned short* qh  = QF + (size_t)(b * 16 + h) * 262144 + qt * 4096;
  const unsigned short* khp = KF + (size_t)(b * 4 + kh) * 262144;
  const unsigned short* vhp = VF + (size_t)(b * 4 + kh) * 262144;

  short8 qf[8];
  #pragma unroll
  for (int s = 0; s < 8; s++)
    qf[s] = *(const short8*)(qh + s * 512 + lane * 8);

  short8 ones;
  #pragma unroll
  for (int e = 0; e < 8; e++) ones[e] = (short)0x3F80;   // bf16 1.0

  float m_r = -3.0e38f;
  f32x16 oacc[4];
  f32x16 lacc;
  #pragma unroll
  for (int dt = 0; dt < 4; dt++)
    #pragma unroll
    for (int r = 0; r < 16; r++) oacc[dt][r] = 0.f;
  #pragma unroll
  for (int r = 0; r < 16; r++) lacc[r] = 0.f;

  // stage kv64-tile kt into buffer buf: 16 K slices + 16 V slices, wave w does 4+4
  // (global_load_lds: per-lane SRC, wave-uniform LDS base; HW scatters lane i at +16*i)
  auto STAGE = [&](int buf, int kt) {
    #pragma unroll
    for (int c = 0; c < 4; c++) {
      const int sl = w * 4 + c;
      __builtin_amdgcn_global_load_lds(
        (const __attribute__((address_space(1))) unsigned int*)(khp + (size_t)kt * 8192 + sl * 512 + lane * 8),
        (__attribute__((address_space(3))) unsigned int*)(&Kl[buf][sl * 512]), 16, 0, 0);
      __builtin_amdgcn_global_load_lds(
        (const __attribute__((address_space(1))) unsigned int*)(vhp + (size_t)kt * 8192 + sl * 512 + lane * 8),
        (__attribute__((address_space(3))) unsigned int*)(&Vl[buf][sl * 512]), 16, 0, 0);
    }
  };

  STAGE(0, 0);
  int cur = 0;
  for (int kt = 0; kt < nbt; kt++) {
    __syncthreads();                       // compiler drains vmcnt/lgkmcnt -> buf[cur] ready
    if (kt + 1 < nbt) STAGE(cur ^ 1, kt + 1);   // async; in flight across compute
    if (kt < ntw) {
      const int kv0 = kt * 64;
      const unsigned short* Kb = &Kl[cur][0];
      const unsigned short* Vb = &Vl[cur][0];
      // QK^T: S^T[kv][q], two 32x32 tiles
      f32x16 sc[2];
      {
        short8 kf0[8];
        #pragma unroll
        for (int s = 0; s < 8; s++)
          kf0[s] = *(const short8*)(Kb + s * 512 + lane * 8);
        #pragma unroll
        for (int r = 0; r < 16; r++) sc[0][r] = 0.f;
        #pragma unroll
        for (int s = 0; s < 8; s++)
          sc[0] = __builtin_amdgcn_mfma_f32_32x32x16_bf16(kf0[s], qf[s], sc[0], 0, 0, 0);
      }
      {
        short8 kf1[8];
        #pragma unroll
        for (int s = 0; s < 8; s++)
          kf1[s] = *(const short8*)(Kb + (8 + s) * 512 + lane * 8);
        #pragma unroll
        for (int r = 0; r < 16; r++) sc[1][r] = 0.f;
        #pragma unroll
        for (int s = 0; s < 8; s++)
          sc[1] = __builtin_amdgcn_mfma_f32_32x32x16_bf16(kf1[s], qf[s], sc[1], 0, 0, 0);
      }
      // V fragments from LDS (cheap; issue before softmax for overlap)
      short8 vf[4][4];
      #pragma unroll
      for (int dt = 0; dt < 4; dt++)
        #pragma unroll
        for (int ks = 0; ks < 4; ks++)
          vf[dt][ks] = *(const short8*)(Vb + (dt * 4 + ks) * 512 + lane * 8);

      // causal mask (diagonal tile only): C row = kv, col = q
      if (kv0 + 63 > qw) {
        #pragma unroll
        for (int ct = 0; ct < 2; ct++)
          #pragma unroll
          for (int r = 0; r < 16; r++) {
            int kg = kv0 + ct * 32 + (r & 3) + 8 * (r >> 2) + 4 * hf;
            if (kg > qw + l31) sc[ct][r] = -3.0e38f;
          }
      }
      // row max
      float mx[16];
      #pragma unroll
      for (int r = 0; r < 16; r++) mx[r] = fmaxf(sc[0][r], sc[1][r]);
      #pragma unroll
      for (int s2 = 8; s2 >= 1; s2 >>= 1)
        #pragma unroll
        for (int i = 0; i < 8; i++) if (i < s2) mx[i] = fmaxf(mx[i], mx[i + s2]);
      float tm = fmaxf(mx[0], __shfl_xor(mx[0], 32));
      // defer-max rescale (exp2 domain, P <= 2^8)
      if (__any(tm > m_r + 8.0f)) {
        float mn = fmaxf(m_r, tm);
        float al = __builtin_amdgcn_exp2f(m_r - mn);
        m_r = mn;
        #pragma unroll
        for (int r = 0; r < 16; r++) {
          float alr = bcast32(al, (r & 3) + 8 * (r >> 2) + 4 * hf);
          #pragma unroll
          for (int dt = 0; dt < 4; dt++) oacc[dt][r] *= alr;
          lacc[r] *= alr;
        }
      }
      #pragma unroll
      for (int ct = 0; ct < 2; ct++)
        #pragma unroll
        for (int r = 0; r < 16; r++) sc[ct][r] = __builtin_amdgcn_exp2f(sc[ct][r] - m_r);

      // repack P -> A-fragments: 16 cvt_pk + 8 permlane32_swap
      short8 pa[4];
      #pragma unroll
      for (int ks = 0; ks < 4; ks++) {
        const int ct = ks >> 1, kb = (ks & 1) * 8;
        unsigned int A0 = cvtpk_bf16(sc[ct][kb + 0], sc[ct][kb + 1]);
        unsigned int A1 = cvtpk_bf16(sc[ct][kb + 2], sc[ct][kb + 3]);
        unsigned int B0 = cvtpk_bf16(sc[ct][kb + 4], sc[ct][kb + 5]);
        unsigned int B1 = cvtpk_bf16(sc[ct][kb + 6], sc[ct][kb + 7]);
        plswap32(A0, B0);
        plswap32(A1, B1);
        union { unsigned int wds[4]; short8 s8; } u;
        u.wds[0] = A0; u.wds[1] = A1; u.wds[2] = B0; u.wds[3] = B1;
        pa[ks] = u.s8;
      }
      // l accumulation on the matrix pipe
      #pragma unroll
      for (int ks = 0; ks < 4; ks++)
        lacc = __builtin_amdgcn_mfma_f32_32x32x16_bf16(pa[ks], ones, lacc, 0, 0, 0);
      // PV: O[32q x 128d] += P[32x64] * V[64x128]
      #pragma unroll
      for (int dt = 0; dt < 4; dt++)
        #pragma unroll
        for (int ks = 0; ks < 4; ks++)
          oacc[dt] = __builtin_amdgcn_mfma_f32_32x32x16_bf16(pa[ks], vf[dt][ks], oacc[dt], 0, 0, 0);
    }
    cur ^= 1;
  }
  // epilogue: lacc[r] = row sum over all kv (no cross-lane needed)
  #pragma unroll
  for (int r = 0; r < 16; r++) {
    float inv = 1.0f / lacc[r];
    int rloc = (r & 3) + 8 * (r >> 2) + 4 * hf;
    int qgr = qw + rloc;
    unsigned short* orow = O + ((size_t)(b * 2048 + qgr)) * 2048 + h * 128;
    #pragma unroll
    for (int dt = 0; dt < 4; dt++)
      orow[dt * 32 + l31] = f2bf(oacc[dt][r] * inv);
  }
}

// ---------------- launch ----------------
extern "C" void kernel_launch(void* const* d_in, const int* in_sizes, int n_in,
                              void* d_out, int out_size, void* d_ws, size_t ws_size,
                              hipStream_t stream) {
  (void)in_sizes; (void)n_in; (void)out_size; (void)ws_size;
  const float* x  = (const float*)d_in[0];
  const float* Wq = (const float*)d_in[1];
  const float* bq = (const float*)d_in[2];
  const float* Wk = (const float*)d_in[3];
  const float* bk = (const float*)d_in[4];
  const float* Wv = (const float*)d_in[5];
  const float* bv = (const float*)d_in[6];
  const float* Wo = (const float*)d_in[7];
  const float* bo = (const float*)d_in[8];
  const int*   sp = (const int*)d_in[9];

  char* ws = (char*)d_ws;
  unsigned short* xb    = (unsigned short*)ws;                // 16,777,216 B (reused as Obuf)
  unsigned short* Wqkvt = (unsigned short*)(ws + 16777216);   // 12,582,912
  unsigned short* Wot   = (unsigned short*)(ws + 29360128);   //  8,388,608
  unsigned short* QKVb  = (unsigned short*)(ws + 37748736);   // 25,165,824 (bf16 [4096][3072])
  float* cost           = (float*)(ws + 62914560);            //    262,144
  float* sint           = (float*)(ws + 63176704);            //    262,144
  float* bcat           = (float*)(ws + 63438848);            //     12,288

  unsigned short* Obuf = xb;  // xb dead after GEMM1
  unsigned short* QFr = (unsigned short*)d_out;
  unsigned short* KFr = (unsigned short*)((char*)d_out + 16777216);
  unsigned short* VFr = (unsigned short*)((char*)d_out + 20971520);

  prep_all<<<dim3(14604), 256, 0, stream>>>(Wq, Wk, Wv, Wo, bq, bk, bv, x,
                                            Wqkvt, Wot, xb, cost, sint, bcat);
  gemm_bt<true><<<dim3(768), 256, 0, stream>>>(xb, Wqkvt, bcat, QKVb, 4096, 3072, 2048, 24);
  scatter_all<<<dim3(20736), 256, 0, stream>>>(QKVb, cost, sint, sp, QFr, KFr, VFr);
  attn_kernel<<<dim3(512), 256, 0, stream>>>(QFr, KFr, VFr, Obuf);
  gemm_bt<false><<<dim3(512), 256, 0, stream>>>(Obuf, Wot, bo, (float*)d_out, 4096, 2048, 2048, 16);
}

// Round 10
// 207.852 us; speedup vs baseline: 2.4172x; 1.0510x over previous
//
#include <hip/hip_runtime.h>

typedef __attribute__((ext_vector_type(8))) short short8;
typedef __attribute__((ext_vector_type(4))) float f32x4;
typedef __attribute__((ext_vector_type(16))) float f32x16;

#define DEVFN __device__ __forceinline__

DEVFN unsigned short f2bf(float f) {
  unsigned int u = __builtin_bit_cast(unsigned int, f);
  u += 0x7FFFu + ((u >> 16) & 1u);   // RNE
  return (unsigned short)(u >> 16);
}
DEVFN float bf2f(unsigned int u) { return __builtin_bit_cast(float, u << 16); }

DEVFN unsigned int cvtpk_bf16(float lo, float hi) {
  unsigned int d;
  asm("v_cvt_pk_bf16_f32 %0, %1, %2" : "=v"(d) : "v"(lo), "v"(hi));
  return d;
}
DEVFN void plswap32(unsigned int& a, unsigned int& b) {
  asm("v_permlane32_swap_b32 %0, %1" : "+v"(a), "+v"(b));
}
DEVFN float bcast32(float v, int srclane) {
  int r = __builtin_amdgcn_ds_bpermute(srclane * 4, __builtin_bit_cast(int, v));
  return __builtin_bit_cast(float, r);
}

// ================= fused prep: weight transposes + convx + tables + bias =================
__global__ __launch_bounds__(256) void prep_all(
    const float* __restrict__ Wq, const float* __restrict__ Wk, const float* __restrict__ Wv,
    const float* __restrict__ Wo, const float* __restrict__ bq, const float* __restrict__ bk,
    const float* __restrict__ bv, const float* __restrict__ x,
    unsigned short* __restrict__ Wqkvt, unsigned short* __restrict__ Wot,
    unsigned short* __restrict__ xb, float* __restrict__ cost, float* __restrict__ sint,
    float* __restrict__ bcat) {
  __shared__ float lds[32][33];
  const int bid = blockIdx.x, tid = threadIdx.x;
  if (bid < 10240) {
    const float* W; unsigned short* Wt; int ncols, bx, by;
    if (bid < 4096)      { W = Wq; Wt = Wqkvt;                        ncols = 2048; bx = bid & 63; by = bid >> 6; }
    else if (bid < 5120) { int l = bid - 4096; W = Wk; Wt = Wqkvt + (size_t)2048 * 2048; ncols = 512; bx = l & 15; by = l >> 4; }
    else if (bid < 6144) { int l = bid - 5120; W = Wv; Wt = Wqkvt + (size_t)2560 * 2048; ncols = 512; bx = l & 15; by = l >> 4; }
    else                 { int l = bid - 6144; W = Wo; Wt = Wot;      ncols = 2048; bx = l & 63; by = l >> 6; }
    int n0 = bx * 32, k0 = by * 32;
    int tx = tid & 31, ty = tid >> 5;
    #pragma unroll
    for (int i = 0; i < 4; i++) {
      int kr = ty + i * 8;
      lds[kr][tx] = W[(size_t)(k0 + kr) * ncols + n0 + tx];
    }
    __syncthreads();
    #pragma unroll
    for (int i = 0; i < 4; i++) {
      int nr = ty + i * 8;
      Wt[(size_t)(n0 + nr) * 2048 + k0 + tx] = f2bf(lds[tx][nr]);
    }
  } else if (bid < 14336) {
    int gid = (bid - 10240) * 256 + tid;
    const float4* xv = (const float4*)x;
    float4 a = xv[(size_t)gid * 2], b = xv[(size_t)gid * 2 + 1];
    short8 u;
    u[0] = (short)f2bf(a.x); u[1] = (short)f2bf(a.y); u[2] = (short)f2bf(a.z); u[3] = (short)f2bf(a.w);
    u[4] = (short)f2bf(b.x); u[5] = (short)f2bf(b.y); u[6] = (short)f2bf(b.z); u[7] = (short)f2bf(b.w);
    *(short8*)(xb + (size_t)gid * 8) = u;
  } else if (bid < 14592) {
    int gid = (bid - 14336) * 256 + tid;   // 65536
    int pos = gid >> 5, i = gid & 31;
    float theta = powf(10000.0f, -(float)(2 * i) / 64.0f);
    float ang = (float)pos * theta;
    cost[gid] = cosf(ang);
    sint[gid] = sinf(ang);
  } else {
    int i = (bid - 14592) * 256 + tid;     // 3072
    float v;
    if (i < 2048) v = bq[i];
    else if (i < 2560) v = bk[i - 2048];
    else v = bv[i - 2560];
    bcat[i] = v;
  }
}

// ================= fused scatter: ropeQ + ropeK + vtrans (fragment-order outputs) =========
__global__ __launch_bounds__(256) void scatter_all(
    const unsigned short* __restrict__ QKVb, const float* __restrict__ cost,
    const float* __restrict__ sint, const int* __restrict__ spp,
    unsigned short* __restrict__ QFr, unsigned short* __restrict__ KFr,
    unsigned short* __restrict__ VFr) {
  __shared__ __align__(16) unsigned short lds[64 * 128];
  const int bid = blockIdx.x, tid = threadIdx.x;
  if (bid < 20480) {
    int NH, LOG2NH, colOff, gid;
    unsigned short* dst;
    float scale;
    if (bid < 16384) { NH = 16; LOG2NH = 4; colOff = 0;    dst = QFr; scale = 0.12751743f; gid = bid * 256 + tid; }
    else             { NH = 4;  LOG2NH = 2; colOff = 2048; dst = KFr; scale = 1.0f;        gid = (bid - 16384) * 256 + tid; }
    int j = gid & 63;
    int h = (gid >> 6) & (NH - 1);
    int m = gid >> (6 + LOG2NH);
    int t = m & 2047;
    int b = m >> 11;
    const unsigned short* src = QKVb + (size_t)m * 3072 + colOff + h * 128 + 2 * j;
    unsigned int pair = *(const unsigned int*)src;
    float xv = bf2f(pair & 0xFFFFu), yv = bf2f(pair >> 16);
    float rx, ry;
    if (j < 32) {
      int pos = (spp[0] + t) & 2047;
      float c = cost[pos * 32 + j], s = sint[pos * 32 + j];
      rx = xv * c - yv * s;
      ry = xv * s + yv * c;
    } else { rx = xv; ry = yv; }
    rx *= scale; ry *= scale;
    int d0 = 2 * j;
    size_t off = (size_t)(b * NH + h) * 262144 + (t >> 5) * 4096 + (d0 >> 4) * 512
               + ((d0 >> 3) & 1) * 256 + (t & 31) * 8 + (d0 & 7);
    unsigned int outp = (unsigned int)f2bf(rx) | ((unsigned int)f2bf(ry) << 16);
    *(unsigned int*)(dst + off) = outp;
  } else {
    int l = bid - 20480;
    int t0 = (l & 31) * 64;
    int bk = l >> 5;
    const unsigned short* src = QKVb + (size_t)(bk >> 2) * 2048 * 3072 + 2560 + (bk & 3) * 128;
    #pragma unroll
    for (int c = 0; c < 4; c++) {
      int idx = c * 256 + tid;
      int tr = idx >> 4, dc = idx & 15;
      short8 v = *(const short8*)(src + (size_t)(t0 + tr) * 3072 + dc * 8);
      *(short8*)((char*)lds + tr * 256 + 16 * (dc ^ (tr >> 3))) = v;
    }
    __syncthreads();
    unsigned short* dstb = VFr + (size_t)bk * 262144;
    #pragma unroll
    for (int c2 = 0; c2 < 4; c2++) {
      int idx2 = c2 * 256 + tid;
      int tc = idx2 & 7, d = idx2 >> 3;
      short8 u;
      #pragma unroll
      for (int e = 0; e < 8; e++) {
        int t = 8 * tc + e;
        u[e] = *(const short*)((char*)lds + t * 256 + 16 * ((d >> 3) ^ tc) + (d & 7) * 2);
      }
      size_t off = (size_t)(t0 >> 6) * 8192 + ((d >> 5) * 4 + ((tc >> 1) & 3)) * 512
                 + (tc & 1) * 256 + (d & 31) * 8;
      *(short8*)(dstb + off) = u;
    }
  }
}

// ============ GEMM v2: 256x128 tile, BK=64, 8 waves, 3-buf LDS, counted vmcnt ============
// C[M][N] = A[M][K]*Bt[N][K]^T + bias. Pipeline: tile t staged during tile t-2 (3 LDS bufs),
// wait = vmcnt(6) (tile t+1's 6 loads/thread stay in flight) + raw s_barrier — never drain.
// LDS layout per buf: A_lo[128x64] | A_hi[128x64] | B[128x64], each row 128B with XOR slot
// swizzle slot = c8 ^ (row&7) (T2). Staged linearly by global_load_lds from pre-swizzled src.
template<bool BF16OUT>
__global__ __launch_bounds__(512, 1) void gemm256(
    const unsigned short* __restrict__ A, const unsigned short* __restrict__ Bt,
    const float* __restrict__ bias, void* __restrict__ Cout, int M, int N, int K, int NTX) {
  __shared__ __align__(16) unsigned short lds[3][24576];   // 144 KB
  const int tid = threadIdx.x;
  const int lane = tid & 63, w = tid >> 6;
  const int wr = w >> 1, wc = w & 1;          // 4 M-waves x 2 N-waves; 64x64 per wave
  const int f = blockIdx.x;
  const int cpx = gridDim.x >> 3;
  const int fs = (f & 7) * cpx + (f >> 3);    // bijective XCD swizzle (grid % 8 == 0)
  const int m0 = (fs / NTX) * 256, n0 = (fs % NTX) * 128;
  const int NT = K >> 6;

  f32x4 acc[4][4];
  #pragma unroll
  for (int i = 0; i < 4; i++)
    #pragma unroll
    for (int j = 0; j < 4; j++)
      #pragma unroll
      for (int r = 0; r < 4; r++) acc[i][j][r] = 0.f;

  // ---- staging geometry: thread reads global (row = l*64 + tid>>3, c8 = (tid&7)^(row&7))
  // so that the linear global_load_lds dest (tid*16 within 8KB round) realizes the swizzle.
  const int r8 = tid >> 3;
  const int c8 = (tid & 7) ^ (r8 & 7);
  const unsigned short* Asrc = A  + (size_t)(m0 + r8) * K + c8 * 8;
  const unsigned short* Bsrc = Bt + (size_t)(n0 + r8) * K + c8 * 8;
  const int woff = w * 512;                   // ushorts; wave-uniform LDS base, HW adds lane*16B

  auto STAGE = [&](int t) {
    unsigned short* bb = &lds[t % 3][0];
    const unsigned short* as = Asrc + t * 64;
    const unsigned short* bs = Bsrc + t * 64;
    #pragma unroll
    for (int l = 0; l < 2; l++) {
      __builtin_amdgcn_global_load_lds(
        (const __attribute__((address_space(1))) unsigned int*)(as + (size_t)l * 64 * K),
        (__attribute__((address_space(3))) unsigned int*)(bb + l * 4096 + woff), 16, 0, 0);
      __builtin_amdgcn_global_load_lds(
        (const __attribute__((address_space(1))) unsigned int*)(as + (size_t)(128 + l * 64) * K),
        (__attribute__((address_space(3))) unsigned int*)(bb + 8192 + l * 4096 + woff), 16, 0, 0);
      __builtin_amdgcn_global_load_lds(
        (const __attribute__((address_space(1))) unsigned int*)(bs + (size_t)l * 64 * K),
        (__attribute__((address_space(3))) unsigned int*)(bb + 16384 + l * 4096 + woff), 16, 0, 0);
    }
  };

  STAGE(0);
  STAGE(1);

  // ---- read-side lane constants (slot = (ks*4 + (lane>>4)) ^ (lane&7); row&7 == lane&7)
  const int lr = lane & 15;
  const int q4 = lane >> 4;
  const int p7 = lane & 7;
  const int so0 = ((q4 ^ p7) * 8);
  const int so1 = (((q4 ^ 4) ^ p7) * 8);
  const int aBase = ((wr & 2) ? 8192 : 0) + ((wr & 1) * 64 + lr) * 64;
  const int bBase = 16384 + (wc * 64 + lr) * 64;

  for (int t = 0; t < NT; t++) {
    if (t + 1 < NT) asm volatile("s_waitcnt vmcnt(6)" ::: "memory");
    else            asm volatile("s_waitcnt vmcnt(0)" ::: "memory");
    __builtin_amdgcn_sched_barrier(0);
    __builtin_amdgcn_s_barrier();
    __builtin_amdgcn_sched_barrier(0);
    if (t + 2 < NT) STAGE(t + 2);           // lands in buf freed by tile t-1's readers
    const unsigned short* bb = &lds[t % 3][0];
    #pragma unroll
    for (int ks = 0; ks < 2; ks++) {
      const int so = ks ? so1 : so0;
      short8 af[4], bfr[4];
      #pragma unroll
      for (int mi = 0; mi < 4; mi++)
        af[mi] = *(const short8*)(bb + aBase + mi * 1024 + so);
      #pragma unroll
      for (int ni = 0; ni < 4; ni++)
        bfr[ni] = *(const short8*)(bb + bBase + ni * 1024 + so);
      __builtin_amdgcn_s_setprio(1);
      #pragma unroll
      for (int mi = 0; mi < 4; mi++)
        #pragma unroll
        for (int ni = 0; ni < 4; ni++)
          acc[mi][ni] = __builtin_amdgcn_mfma_f32_16x16x32_bf16(af[mi], bfr[ni], acc[mi][ni], 0, 0, 0);
      __builtin_amdgcn_s_setprio(0);
    }
  }

  const int cl = lane & 15, rq = lane >> 4;
  #pragma unroll
  for (int mi = 0; mi < 4; mi++) {
    #pragma unroll
    for (int ni = 0; ni < 4; ni++) {
      int gn = n0 + wc * 64 + ni * 16 + cl;
      float bv = bias[gn];
      #pragma unroll
      for (int r = 0; r < 4; r++) {
        int gm = m0 + wr * 64 + mi * 16 + rq * 4 + r;
        float v = acc[mi][ni][r] + bv;
        if (BF16OUT) ((unsigned short*)Cout)[(size_t)gm * N + gn] = f2bf(v);
        else ((float*)Cout)[(size_t)gm * N + gn] = v;
      }
    }
  }
}

// ---------------- flash attention v9: LDS-shared K/V (global_load_lds dbuf), 4 waves -----
__global__ __launch_bounds__(256, 2) void attn_kernel(
    const unsigned short* __restrict__ QF, const unsigned short* __restrict__ KF,
    const unsigned short* __restrict__ VF, unsigned short* __restrict__ O) {
  __shared__ __align__(16) unsigned short Kl[2][8192];
  __shared__ __align__(16) unsigned short Vl[2][8192];

  const int tid = threadIdx.x;
  const int lane = tid & 63;
  const int w = tid >> 6;
  const int l31 = lane & 31;
  const int hf = lane >> 5;
  const int bid = blockIdx.x;
  const int g8 = bid & 7;
  const int b = g8 >> 2, kh = g8 & 3;
  const int h = kh * 4 + ((bid >> 3) & 3);
  const int qg = (bid < 256) ? (bid >> 5) : (15 - ((bid - 256) >> 5));
  const int qt = qg * 4 + w;
  const int qw = qt * 32;
  const int ntw = (qt >> 1) + 1;
  const int nbt = 2 * qg + 2;

  const unsigned short* qh  = QF + (size_t)(b * 16 + h) * 262144 + qt * 4096;
  const unsigned short* khp = KF + (size_t)(b * 4 + kh) * 262144;
  const unsigned short* vhp = VF + (size_t)(b * 4 + kh) * 262144;

  short8 qf[8];
  #pragma unroll
  for (int s = 0; s < 8; s++)
    qf[s] = *(const short8*)(qh + s * 512 + lane * 8);

  short8 ones;
  #pragma unroll
  for (int e = 0; e < 8; e++) ones[e] = (short)0x3F80;

  float m_r = -3.0e38f;
  f32x16 oacc[4];
  f32x16 lacc;
  #pragma unroll
  for (int dt = 0; dt < 4; dt++)
    #pragma unroll
    for (int r = 0; r < 16; r++) oacc[dt][r] = 0.f;
  #pragma unroll
  for (int r = 0; r < 16; r++) lacc[r] = 0.f;

  auto STAGE = [&](int buf, int kt) {
    #pragma unroll
    for (int c = 0; c < 4; c++) {
      const int sl = w * 4 + c;
      __builtin_amdgcn_global_load_lds(
        (const __attribute__((address_space(1))) unsigned int*)(khp + (size_t)kt * 8192 + sl * 512 + lane * 8),
        (__attribute__((address_space(3))) unsigned int*)(&Kl[buf][sl * 512]), 16, 0, 0);
      __builtin_amdgcn_global_load_lds(
        (const __attribute__((address_space(1))) unsigned int*)(vhp + (size_t)kt * 8192 + sl * 512 + lane * 8),
        (__attribute__((address_space(3))) unsigned int*)(&Vl[buf][sl * 512]), 16, 0, 0);
    }
  };

  STAGE(0, 0);
  int cur = 0;
  for (int kt = 0; kt < nbt; kt++) {
    __syncthreads();
    if (kt + 1 < nbt) STAGE(cur ^ 1, kt + 1);
    if (kt < ntw) {
      const int kv0 = kt * 64;
      const unsigned short* Kb = &Kl[cur][0];
      const unsigned short* Vb = &Vl[cur][0];
      f32x16 sc[2];
      {
        short8 kf0[8];
        #pragma unroll
        for (int s = 0; s < 8; s++)
          kf0[s] = *(const short8*)(Kb + s * 512 + lane * 8);
        #pragma unroll
        for (int r = 0; r < 16; r++) sc[0][r] = 0.f;
        #pragma unroll
        for (int s = 0; s < 8; s++)
          sc[0] = __builtin_amdgcn_mfma_f32_32x32x16_bf16(kf0[s], qf[s], sc[0], 0, 0, 0);
      }
      {
        short8 kf1[8];
        #pragma unroll
        for (int s = 0; s < 8; s++)
          kf1[s] = *(const short8*)(Kb + (8 + s) * 512 + lane * 8);
        #pragma unroll
        for (int r = 0; r < 16; r++) sc[1][r] = 0.f;
        #pragma unroll
        for (int s = 0; s < 8; s++)
          sc[1] = __builtin_amdgcn_mfma_f32_32x32x16_bf16(kf1[s], qf[s], sc[1], 0, 0, 0);
      }
      short8 vf[4][4];
      #pragma unroll
      for (int dt = 0; dt < 4; dt++)
        #pragma unroll
        for (int ks = 0; ks < 4; ks++)
          vf[dt][ks] = *(const short8*)(Vb + (dt * 4 + ks) * 512 + lane * 8);

      if (kv0 + 63 > qw) {
        #pragma unroll
        for (int ct = 0; ct < 2; ct++)
          #pragma unroll
          for (int r = 0; r < 16; r++) {
            int kg = kv0 + ct * 32 + (r & 3) + 8 * (r >> 2) + 4 * hf;
            if (kg > qw + l31) sc[ct][r] = -3.0e38f;
          }
      }
      float mx[16];
      #pragma unroll
      for (int r = 0; r < 16; r++) mx[r] = fmaxf(sc[0][r], sc[1][r]);
      #pragma unroll
      for (int s2 = 8; s2 >= 1; s2 >>= 1)
        #pragma unroll
        for (int i = 0; i < 8; i++) if (i < s2) mx[i] = fmaxf(mx[i], mx[i + s2]);
      float tm = fmaxf(mx[0], __shfl_xor(mx[0], 32));
      if (__any(tm > m_r + 8.0f)) {
        float mn = fmaxf(m_r, tm);
        float al = __builtin_amdgcn_exp2f(m_r - mn);
        m_r = mn;
        #pragma unroll
        for (int r = 0; r < 16; r++) {
          float alr = bcast32(al, (r & 3) + 8 * (r >> 2) + 4 * hf);
          #pragma unroll
          for (int dt = 0; dt < 4; dt++) oacc[dt][r] *= alr;
          lacc[r] *= alr;
        }
      }
      #pragma unroll
      for (int ct = 0; ct < 2; ct++)
        #pragma unroll
        for (int r = 0; r < 16; r++) sc[ct][r] = __builtin_amdgcn_exp2f(sc[ct][r] - m_r);

      short8 pa[4];
      #pragma unroll
      for (int ks = 0; ks < 4; ks++) {
        const int ct = ks >> 1, kb = (ks & 1) * 8;
        unsigned int A0 = cvtpk_bf16(sc[ct][kb + 0], sc[ct][kb + 1]);
        unsigned int A1 = cvtpk_bf16(sc[ct][kb + 2], sc[ct][kb + 3]);
        unsigned int B0 = cvtpk_bf16(sc[ct][kb + 4], sc[ct][kb + 5]);
        unsigned int B1 = cvtpk_bf16(sc[ct][kb + 6], sc[ct][kb + 7]);
        plswap32(A0, B0);
        plswap32(A1, B1);
        union { unsigned int wds[4]; short8 s8; } u;
        u.wds[0] = A0; u.wds[1] = A1; u.wds[2] = B0; u.wds[3] = B1;
        pa[ks] = u.s8;
      }
      #pragma unroll
      for (int ks = 0; ks < 4; ks++)
        lacc = __builtin_amdgcn_mfma_f32_32x32x16_bf16(pa[ks], ones, lacc, 0, 0, 0);
      #pragma unroll
      for (int dt = 0; dt < 4; dt++)
        #pragma unroll
        for (int ks = 0; ks < 4; ks++)
          oacc[dt] = __builtin_amdgcn_mfma_f32_32x32x16_bf16(pa[ks], vf[dt][ks], oacc[dt], 0, 0, 0);
    }
    cur ^= 1;
  }
  #pragma unroll
  for (int r = 0; r < 16; r++) {
    float inv = 1.0f / lacc[r];
    int rloc = (r & 3) + 8 * (r >> 2) + 4 * hf;
    int qgr = qw + rloc;
    unsigned short* orow = O + ((size_t)(b * 2048 + qgr)) * 2048 + h * 128;
    #pragma unroll
    for (int dt = 0; dt < 4; dt++)
      orow[dt * 32 + l31] = f2bf(oacc[dt][r] * inv);
  }
}

// ---------------- launch ----------------
extern "C" void kernel_launch(void* const* d_in, const int* in_sizes, int n_in,
                              void* d_out, int out_size, void* d_ws, size_t ws_size,
                              hipStream_t stream) {
  (void)in_sizes; (void)n_in; (void)out_size; (void)ws_size;
  const float* x  = (const float*)d_in[0];
  const float* Wq = (const float*)d_in[1];
  const float* bq = (const float*)d_in[2];
  const float* Wk = (const float*)d_in[3];
  const float* bk = (const float*)d_in[4];
  const float* Wv = (const float*)d_in[5];
  const float* bv = (const float*)d_in[6];
  const float* Wo = (const float*)d_in[7];
  const float* bo = (const float*)d_in[8];
  const int*   sp = (const int*)d_in[9];

  char* ws = (char*)d_ws;
  unsigned short* xb    = (unsigned short*)ws;                // 16,777,216 B (reused as Obuf)
  unsigned short* Wqkvt = (unsigned short*)(ws + 16777216);   // 12,582,912
  unsigned short* Wot   = (unsigned short*)(ws + 29360128);   //  8,388,608
  unsigned short* QKVb  = (unsigned short*)(ws + 37748736);   // 25,165,824 (bf16 [4096][3072])
  float* cost           = (float*)(ws + 62914560);            //    262,144
  float* sint           = (float*)(ws + 63176704);            //    262,144
  float* bcat           = (float*)(ws + 63438848);            //     12,288

  unsigned short* Obuf = xb;  // xb dead after GEMM1
  unsigned short* QFr = (unsigned short*)d_out;
  unsigned short* KFr = (unsigned short*)((char*)d_out + 16777216);
  unsigned short* VFr = (unsigned short*)((char*)d_out + 20971520);

  prep_all<<<dim3(14604), 256, 0, stream>>>(Wq, Wk, Wv, Wo, bq, bk, bv, x,
                                            Wqkvt, Wot, xb, cost, sint, bcat);
  gemm256<true><<<dim3(384), 512, 0, stream>>>(xb, Wqkvt, bcat, QKVb, 4096, 3072, 2048, 24);
  scatter_all<<<dim3(20736), 256, 0, stream>>>(QKVb, cost, sint, sp, QFr, KFr, VFr);
  attn_kernel<<<dim3(512), 256, 0, stream>>>(QFr, KFr, VFr, Obuf);
  gemm256<false><<<dim3(256), 512, 0, stream>>>(Obuf, Wot, bo, (float*)d_out, 4096, 2048, 2048, 16);
}